// Round 6
// baseline (8375.627 us; speedup 1.0000x reference)
//
#include <hip/hip_runtime.h>
#include <math.h>

#define DEVFN __device__ __forceinline__

constexpr int NB   = 16;     // batch
constexpr int NPTS = 8192;   // N points
constexpr int NG   = 128;    // groups
constexpr int NK   = 32;     // knn
constexpr int NC   = 384;    // model dim
constexpr int NH   = 6;      // heads
constexpr int NL   = 12;     // layers
constexpr int NHID = 1536;   // mlp hidden
constexpr int NDH  = 64;     // head dim
constexpr float LN_EPS = 1e-5f;

// fp32 ops without fma contraction, to track numpy's rounding in the
// index-selection stages (FPS / kNN / path ordering).
DEVFN float sq3(float x, float y, float z) {
  return __fadd_rn(__fadd_rn(__fmul_rn(x, x), __fmul_rn(y, y)), __fmul_rn(z, z));
}
DEVFN float dot3(float ax, float ay, float az, float bx, float by, float bz) {
  return __fadd_rn(__fadd_rn(__fmul_rn(ax, bx), __fmul_rn(ay, by)), __fmul_rn(az, bz));
}

// ---------------- 1. farthest point sampling (one block per batch) ----------------
__global__ __launch_bounds__(512) void fps_kernel(const float* __restrict__ xyz,
                                                  int* __restrict__ cent) {
  __shared__ float dist[NPTS];
  __shared__ float rv[512];
  __shared__ int   ri[512];
  const int b = blockIdx.x, t = threadIdx.x;
  const float* X = xyz + (size_t)b * NPTS * 3;
  for (int i = t; i < NPTS; i += 512) dist[i] = 1e10f;
  __syncthreads();
  int far = 0;
  for (int s = 0; s < NG; ++s) {
    if (t == 0) cent[b * NG + s] = far;
    const float cx = X[far * 3 + 0], cy = X[far * 3 + 1], cz = X[far * 3 + 2];
    float bv = -1.0f; int bi = 0;
    for (int i = t; i < NPTS; i += 512) {
      float dx = __fsub_rn(X[i * 3 + 0], cx);
      float dy = __fsub_rn(X[i * 3 + 1], cy);
      float dz = __fsub_rn(X[i * 3 + 2], cz);
      float d  = sq3(dx, dy, dz);
      float nd = fminf(dist[i], d);
      dist[i] = nd;
      if (nd > bv) { bv = nd; bi = i; }   // first-occurrence within strided subset
    }
    rv[t] = bv; ri[t] = bi;
    __syncthreads();
    for (int o = 256; o > 0; o >>= 1) {
      if (t < o) {
        if (rv[t + o] > rv[t] || (rv[t + o] == rv[t] && ri[t + o] < ri[t])) {
          rv[t] = rv[t + o]; ri[t] = ri[t + o];
        }
      }
      __syncthreads();
    }
    far = ri[0];
    __syncthreads();
  }
}

// ---------------- 2. kNN (one block per (b,g) center) ----------------
__global__ __launch_bounds__(256) void knn_kernel(const float* __restrict__ xyz,
                                                  const int* __restrict__ cent,
                                                  float* __restrict__ center,
                                                  int* __restrict__ knn) {
  __shared__ float d2s[NPTS];
  __shared__ float rv[256];
  __shared__ int   ri[256];
  const int bg = blockIdx.x, t = threadIdx.x;
  const int b = bg >> 7;
  const float* X = xyz + (size_t)b * NPTS * 3;
  const int ci = cent[bg];
  const float cx = X[ci * 3 + 0], cy = X[ci * 3 + 1], cz = X[ci * 3 + 2];
  if (t == 0) { center[bg * 3 + 0] = cx; center[bg * 3 + 1] = cy; center[bg * 3 + 2] = cz; }
  const float ra = sq3(cx, cy, cz);
  for (int i = t; i < NPTS; i += 256) {
    float x = X[i * 3 + 0], y = X[i * 3 + 1], z = X[i * 3 + 2];
    float rb = sq3(x, y, z);
    float dt = dot3(cx, cy, cz, x, y, z);
    // match reference: max(0, (ra+rb) - 2*dot)
    d2s[i] = fmaxf(__fsub_rn(__fadd_rn(ra, rb), __fmul_rn(2.0f, dt)), 0.0f);
  }
  __syncthreads();
  for (int k = 0; k < NK; ++k) {
    float bv = 3.0e38f; int bi = 0;
    for (int i = t; i < NPTS; i += 256) {
      float v = d2s[i];
      if (v < bv) { bv = v; bi = i; }
    }
    rv[t] = bv; ri[t] = bi;
    __syncthreads();
    for (int o = 128; o > 0; o >>= 1) {
      if (t < o) {
        if (rv[t + o] < rv[t] || (rv[t + o] == rv[t] && ri[t + o] < ri[t])) {
          rv[t] = rv[t + o]; ri[t] = ri[t + o];
        }
      }
      __syncthreads();
    }
    if (t == 0) { knn[(size_t)bg * NK + k] = ri[0]; d2s[ri[0]] = 3.0e38f; }
    __syncthreads();
  }
}

// ---------------- 3. greedy nearest path over centers (one block per batch) ----------------
__global__ __launch_bounds__(128) void order_kernel(const float* __restrict__ center,
                                                    int* __restrict__ order) {
  __shared__ float cx[NG], cy[NG], cz[NG];
  __shared__ int   vis[NG];
  __shared__ float rv[NG];
  __shared__ int   ri[NG];
  const int b = blockIdx.x, t = threadIdx.x;
  cx[t] = center[((size_t)b * NG + t) * 3 + 0];
  cy[t] = center[((size_t)b * NG + t) * 3 + 1];
  cz[t] = center[((size_t)b * NG + t) * 3 + 2];
  vis[t] = (t == 0) ? 1 : 0;
  if (t == 0) order[b * NG] = 0;
  __syncthreads();
  int last = 0;
  for (int s = 1; s < NG; ++s) {
    float d;
    if (vis[t]) {
      d = 3.0e38f;
    } else {
      const float lx = cx[last], ly = cy[last], lz = cz[last];
      float ra = sq3(lx, ly, lz), rb = sq3(cx[t], cy[t], cz[t]);
      float dd = __fsub_rn(__fadd_rn(ra, rb), __fmul_rn(2.0f, dot3(lx, ly, lz, cx[t], cy[t], cz[t])));
      d = fmaxf(dd, 0.0f);
    }
    rv[t] = d; ri[t] = t;
    __syncthreads();
    for (int o = 64; o > 0; o >>= 1) {
      if (t < o) {
        if (rv[t + o] < rv[t] || (rv[t + o] == rv[t] && ri[t + o] < ri[t])) {
          rv[t] = rv[t + o]; ri[t] = ri[t + o];
        }
      }
      __syncthreads();
    }
    last = ri[0];
    if (t == 0) order[b * NG + s] = last;
    if (t == last) vis[t] = 1;
    __syncthreads();
  }
}

// ---------------- 4. gather ordered neighborhoods ----------------
__global__ void gather_neigh(const float* __restrict__ xyz, const int* __restrict__ knn,
                             const int* __restrict__ order, const float* __restrict__ center,
                             float* __restrict__ neigh, float* __restrict__ cord) {
  const int bg = blockIdx.x, t = threadIdx.x;  // 32 threads
  const int b = bg >> 7;
  const int src = order[bg];
  const int sbg = (b << 7) + src;
  const float c0 = center[sbg * 3 + 0], c1 = center[sbg * 3 + 1], c2 = center[sbg * 3 + 2];
  if (t < 3) cord[bg * 3 + t] = center[sbg * 3 + t];
  const int idx = knn[(size_t)sbg * NK + t];
  const float* P = xyz + ((size_t)b * NPTS + idx) * 3;
  float* o = neigh + ((size_t)bg * NK + t) * 3;
  o[0] = __fsub_rn(P[0], c0);
  o[1] = __fsub_rn(P[1], c1);
  o[2] = __fsub_rn(P[2], c2);
}

// ---------------- 5. encoder: BN1 statistics ----------------
__global__ __launch_bounds__(128) void bn1_stats(const float* __restrict__ neigh,
                                                 const float* __restrict__ w,
                                                 const float* __restrict__ bias,
                                                 float* __restrict__ psum,
                                                 float* __restrict__ psq) {
  const int c = threadIdx.x, blk = blockIdx.x;   // 256 blocks x 128 ch
  const float wx = w[c * 3 + 0], wy = w[c * 3 + 1], wz = w[c * 3 + 2], bb = bias[c];
  float s = 0.f, s2 = 0.f;
  const float* nr = neigh + (size_t)blk * 256 * 3;
  for (int r = 0; r < 256; ++r) {
    float y = fmaf(nr[r * 3 + 2], wz, fmaf(nr[r * 3 + 1], wy, fmaf(nr[r * 3 + 0], wx, bb)));
    s += y; s2 = fmaf(y, y, s2);
  }
  psum[c * 256 + blk] = s;
  psq[c * 256 + blk]  = s2;
}

__global__ __launch_bounds__(256) void bn1_reduce(const float* __restrict__ psum,
                                                  const float* __restrict__ psq,
                                                  const float* __restrict__ g,
                                                  const float* __restrict__ b,
                                                  float* __restrict__ A, float* __restrict__ B0) {
  __shared__ double rs[256], rq[256];
  const int c = blockIdx.x, t = threadIdx.x;
  rs[t] = (double)psum[c * 256 + t];
  rq[t] = (double)psq[c * 256 + t];
  __syncthreads();
  for (int o = 128; o > 0; o >>= 1) {
    if (t < o) { rs[t] += rs[t + o]; rq[t] += rq[t + o]; }
    __syncthreads();
  }
  if (t == 0) {
    const double M = 65536.0;
    double m = rs[0] / M;
    double v = rq[0] / M - m * m;
    if (v < 0) v = 0;
    float a = g[c] * rsqrtf((float)v + LN_EPS);
    A[c] = a;
    B0[c] = b[c] - (float)m * a;
  }
}

// ---------------- encoder shared-memory layout (dynamic LDS) ----------------
// floats: ns[128] | gm[256] | f2[32*256] | ubuf[4224] (f1 32x128 | W3t 32x132)
//         | stile[32*128] | w4t[8*388] (tokens kernel only)
constexpr int SM_NS    = 0;
constexpr int SM_GM    = 128;
constexpr int SM_F2    = 384;
constexpr int SM_UBUF  = 384 + 32 * 256;           // 8576
constexpr int SM_STILE = SM_UBUF + 32 * 132;       // 12800
constexpr int SM_W4T   = SM_STILE + 32 * 128;      // 16896
constexpr int SM_E2_FLOATS = SM_W4T;               // 16896 -> 67584 B
constexpr int SM_E3_FLOATS = SM_W4T + 8 * 388;     // 20000 -> 80000 B

// phase A: f1 = relu(bn1(neigh@ec1w^T)) ; f2 = f1@ec2w^T + ec2b ; gm = colmax(f2)
__device__ __forceinline__ void enc_phaseA(int bg, int t, const float* __restrict__ neigh,
                                           const float* __restrict__ ec1w, const float* __restrict__ ec1b,
                                           const float* __restrict__ A1, const float* __restrict__ B01,
                                           const float* __restrict__ ec2w, const float* __restrict__ ec2b,
                                           float* ns, float* f1 /*32x128*/, float* f2 /*32x256*/, float* gm) {
  if (t < 96) ns[t] = neigh[(size_t)bg * 96 + t];
  __syncthreads();
  for (int e = t; e < 32 * 128; e += 256) {
    const int r = e >> 7, c = e & 127;
    float y = fmaf(ns[r * 3 + 2], ec1w[c * 3 + 2],
             fmaf(ns[r * 3 + 1], ec1w[c * 3 + 1],
             fmaf(ns[r * 3 + 0], ec1w[c * 3 + 0], ec1b[c])));
    y = fmaf(y, A1[c], B01[c]);
    f1[r * 128 + c] = fmaxf(y, 0.f);
  }
  __syncthreads();
  {
    const int c = t;   // one output column per thread
    float acc[32];
#pragma unroll
    for (int r = 0; r < 32; ++r) acc[r] = ec2b[c];
    const float4* wr = (const float4*)(ec2w + (size_t)c * 128);
    for (int j = 0; j < 32; ++j) {
      const float4 wv = wr[j];
#pragma unroll
      for (int r = 0; r < 32; ++r) {
        const float4 fv = *(const float4*)&f1[r * 128 + j * 4];
        acc[r] = fmaf(fv.w, wv.w, fmaf(fv.z, wv.z, fmaf(fv.y, wv.y, fmaf(fv.x, wv.x, acc[r]))));
      }
    }
    float m = -3.0e38f;
#pragma unroll
    for (int r = 0; r < 32; ++r) { f2[r * 256 + c] = acc[r]; m = fmaxf(m, acc[r]); }
    gm[c] = m;
  }
  __syncthreads();
}

// mm3 for one 128-column tile: stile = x3 @ sc1w^T + sc1b (x3 = [gm | f2])
// gm part is row-constant -> computed once per column (acc0), then replicated.
__device__ __forceinline__ void mm3_tile(int n3, int t,
                                         const float* __restrict__ sc1w, const float* __restrict__ sc1b,
                                         const float* gm, const float* f2,
                                         float* w3t /*32x132*/, float* stile /*32x128*/) {
  const int rx = t >> 5, cx = t & 31;
  float acc0[4] = {0.f, 0.f, 0.f, 0.f};
  float acc[4][4];
  for (int k3 = 0; k3 < 16; ++k3) {
    // stage W3t[kk][c] <- sc1w[n3*128+c][k3*32+kk]
    for (int idx = t; idx < 1024; idx += 256) {
      const int c = idx >> 3, j = idx & 7;
      const float4 wv = *(const float4*)(sc1w + (size_t)(n3 * 128 + c) * 512 + k3 * 32 + j * 4);
      w3t[(j * 4 + 0) * 132 + c] = wv.x;
      w3t[(j * 4 + 1) * 132 + c] = wv.y;
      w3t[(j * 4 + 2) * 132 + c] = wv.z;
      w3t[(j * 4 + 3) * 132 + c] = wv.w;
    }
    __syncthreads();
    if (k3 == 8) {
#pragma unroll
      for (int j = 0; j < 4; ++j) {
        acc[0][j] = acc0[j]; acc[1][j] = acc0[j]; acc[2][j] = acc0[j]; acc[3][j] = acc0[j];
      }
    }
    if (k3 < 8) {
#pragma unroll
      for (int kk = 0; kk < 32; ++kk) {
        const float a = gm[k3 * 32 + kk];
        const float4 w = *(const float4*)(w3t + kk * 132 + cx * 4);
        acc0[0] = fmaf(a, w.x, acc0[0]); acc0[1] = fmaf(a, w.y, acc0[1]);
        acc0[2] = fmaf(a, w.z, acc0[2]); acc0[3] = fmaf(a, w.w, acc0[3]);
      }
    } else {
#pragma unroll
      for (int kk = 0; kk < 32; ++kk) {
        const float4 w = *(const float4*)(w3t + kk * 132 + cx * 4);
#pragma unroll
        for (int i = 0; i < 4; ++i) {
          const float a = f2[(rx * 4 + i) * 256 + k3 * 32 + kk - 256];
          acc[i][0] = fmaf(a, w.x, acc[i][0]); acc[i][1] = fmaf(a, w.y, acc[i][1]);
          acc[i][2] = fmaf(a, w.z, acc[i][2]); acc[i][3] = fmaf(a, w.w, acc[i][3]);
        }
      }
    }
    __syncthreads();
  }
#pragma unroll
  for (int i = 0; i < 4; ++i)
#pragma unroll
    for (int j = 0; j < 4; ++j)
      stile[(rx * 4 + i) * 128 + cx * 4 + j] = acc[i][j] + sc1b[n3 * 128 + cx * 4 + j];
}

// mm4 accumulation for one 128-k slice (the n3-th mm3 tile, post bn2+relu in stile)
__device__ __forceinline__ void mm4_acc(int n3, int t, const float* __restrict__ sc2w,
                                        const float* stile, float* w4t /*8x388*/,
                                        float acc4[4][12]) {
  const int rx = t >> 5, cy = t & 31;
  for (int ks = 0; ks < 16; ++ks) {
    for (int idx = t; idx < 768; idx += 256) {
      const int n = idx >> 1, h = idx & 1;
      const float4 wv = *(const float4*)(sc2w + (size_t)n * 512 + n3 * 128 + ks * 8 + h * 4);
      w4t[(h * 4 + 0) * 388 + n] = wv.x;
      w4t[(h * 4 + 1) * 388 + n] = wv.y;
      w4t[(h * 4 + 2) * 388 + n] = wv.z;
      w4t[(h * 4 + 3) * 388 + n] = wv.w;
    }
    __syncthreads();
#pragma unroll
    for (int kk = 0; kk < 8; ++kk) {
      float a[4];
#pragma unroll
      for (int i = 0; i < 4; ++i) a[i] = stile[(rx * 4 + i) * 128 + ks * 8 + kk];
#pragma unroll
      for (int j4 = 0; j4 < 3; ++j4) {
        const float4 w = *(const float4*)(w4t + kk * 388 + cy * 12 + j4 * 4);
#pragma unroll
        for (int i = 0; i < 4; ++i) {
          acc4[i][j4 * 4 + 0] = fmaf(a[i], w.x, acc4[i][j4 * 4 + 0]);
          acc4[i][j4 * 4 + 1] = fmaf(a[i], w.y, acc4[i][j4 * 4 + 1]);
          acc4[i][j4 * 4 + 2] = fmaf(a[i], w.z, acc4[i][j4 * 4 + 2]);
          acc4[i][j4 * 4 + 3] = fmaf(a[i], w.w, acc4[i][j4 * 4 + 3]);
        }
      }
    }
    __syncthreads();
  }
}

// ---------------- 6. encoder: BN2 statistics ----------------
__global__ __launch_bounds__(256) void enc_stats2b(const float* __restrict__ neigh,
                                                   const float* __restrict__ ec1w, const float* __restrict__ ec1b,
                                                   const float* __restrict__ A1, const float* __restrict__ B01,
                                                   const float* __restrict__ ec2w, const float* __restrict__ ec2b,
                                                   const float* __restrict__ sc1w, const float* __restrict__ sc1b,
                                                   float* __restrict__ psum, float* __restrict__ psq) {
  extern __shared__ float sm[];
  float* ns = sm + SM_NS; float* gm = sm + SM_GM; float* f2 = sm + SM_F2;
  float* ubuf = sm + SM_UBUF; float* stile = sm + SM_STILE;
  const int bg = blockIdx.x, t = threadIdx.x;
  enc_phaseA(bg, t, neigh, ec1w, ec1b, A1, B01, ec2w, ec2b, ns, ubuf, f2, gm);
  for (int n3 = 0; n3 < 4; ++n3) {
    mm3_tile(n3, t, sc1w, sc1b, gm, f2, ubuf, stile);
    __syncthreads();
    if (t < 128) {
      const int cg = n3 * 128 + t;
      float s = 0.f, q = 0.f;
      for (int r = 0; r < 32; ++r) {
        const float v = stile[r * 128 + t];
        s += v; q = fmaf(v, v, q);
      }
      psum[(size_t)cg * 2048 + bg] = s;
      psq[(size_t)cg * 2048 + bg]  = q;
    }
    __syncthreads();
  }
}

__global__ __launch_bounds__(256) void bn2_reduce(const float* __restrict__ psum,
                                                  const float* __restrict__ psq,
                                                  const float* __restrict__ g,
                                                  const float* __restrict__ b,
                                                  float* __restrict__ A, float* __restrict__ B0) {
  __shared__ double rs[256], rq[256];
  const int c = blockIdx.x, t = threadIdx.x;
  double s = 0.0, q = 0.0;
  for (int i = t; i < 2048; i += 256) {
    s += (double)psum[(size_t)c * 2048 + i];
    q += (double)psq[(size_t)c * 2048 + i];
  }
  rs[t] = s; rq[t] = q;
  __syncthreads();
  for (int o = 128; o > 0; o >>= 1) {
    if (t < o) { rs[t] += rs[t + o]; rq[t] += rq[t + o]; }
    __syncthreads();
  }
  if (t == 0) {
    const double M = 65536.0;
    double m = rs[0] / M;
    double v = rq[0] / M - m * m;
    if (v < 0) v = 0;
    float a = g[c] * rsqrtf((float)v + LN_EPS);
    A[c] = a;
    B0[c] = b[c] - (float)m * a;
  }
}

// ---------------- 7. encoder: tokens ----------------
__global__ __launch_bounds__(256) void enc_tokens2(const float* __restrict__ neigh,
                                                   const float* __restrict__ ec1w, const float* __restrict__ ec1b,
                                                   const float* __restrict__ A1, const float* __restrict__ B01,
                                                   const float* __restrict__ ec2w, const float* __restrict__ ec2b,
                                                   const float* __restrict__ sc1w, const float* __restrict__ sc1b,
                                                   const float* __restrict__ A2, const float* __restrict__ B02,
                                                   const float* __restrict__ sc2w, const float* __restrict__ sc2b,
                                                   float* __restrict__ tokens) {
  extern __shared__ float sm[];
  float* ns = sm + SM_NS; float* gm = sm + SM_GM; float* f2 = sm + SM_F2;
  float* ubuf = sm + SM_UBUF; float* stile = sm + SM_STILE; float* w4t = sm + SM_W4T;
  const int bg = blockIdx.x, t = threadIdx.x;
  enc_phaseA(bg, t, neigh, ec1w, ec1b, A1, B01, ec2w, ec2b, ns, ubuf, f2, gm);
  float acc4[4][12] = {};
  for (int n3 = 0; n3 < 4; ++n3) {
    mm3_tile(n3, t, sc1w, sc1b, gm, f2, ubuf, stile);
    __syncthreads();
    for (int e = t; e < 32 * 128; e += 256) {
      const int r = e >> 7, c = e & 127, cg = n3 * 128 + c;
      stile[r * 128 + c] = fmaxf(fmaf(stile[r * 128 + c], A2[cg], B02[cg]), 0.f);
    }
    __syncthreads();
    mm4_acc(n3, t, sc2w, stile, w4t, acc4);
  }
  // maxpool over the 32 rows: thread-local over its 4 rows, then across 8 row-groups
  const int rx = t >> 5, cy = t & 31;
  float* tk = stile;   // reuse (needs 8*384 <= 4096)
  __syncthreads();
#pragma unroll
  for (int j = 0; j < 12; ++j) {
    const float m = fmaxf(fmaxf(acc4[0][j], acc4[1][j]), fmaxf(acc4[2][j], acc4[3][j]));
    tk[rx * 384 + cy * 12 + j] = m;
  }
  __syncthreads();
  for (int c = t; c < NC; c += 256) {
    float m = tk[c];
#pragma unroll
    for (int r = 1; r < 8; ++r) m = fmaxf(m, tk[r * 384 + c]);
    tokens[(size_t)bg * NC + c] = m + sc2b[c];
  }
}

// ---------------- 8. positional embedding + h init ----------------
__global__ void pos_kernel(const float* __restrict__ cord, float* __restrict__ pos) {
  const int tok = blockIdx.x, t = threadIdx.x;   // 384 threads
  const int c = t >> 7;
  const int rem = t & 127;
  const int i = rem >> 1;
  const int isc = rem & 1;
  const float coord = cord[tok * 3 + c];
  const float ex = 2.0f * (float)i / 128.0f;
  const float inv = 1.0f / powf(10000.0f, ex);
  const float ang = coord * inv;
  pos[(size_t)tok * NC + t] = isc ? cosf(ang) : sinf(ang);
}

__global__ void hinit_kernel(const float* __restrict__ tokens, const float* __restrict__ sos,
                             float* __restrict__ h) {
  const int tok = blockIdx.x, t = threadIdx.x;   // 384 threads
  const int b = tok >> 7, g = tok & 127;
  const float v = (g == 0) ? sos[t] : tokens[((size_t)b * NG + (g - 1)) * NC + t];
  h[(size_t)tok * NC + t] = v;
}

// ---------------- 9. layernorm ----------------
__global__ __launch_bounds__(128) void ln_kernel(const float* __restrict__ in,
                                                 const float* __restrict__ add,
                                                 const float* __restrict__ g,
                                                 const float* __restrict__ b,
                                                 float* __restrict__ y,
                                                 float* __restrict__ xout) {
  __shared__ float red[128];
  const int row = blockIdx.x, t = threadIdx.x;
  const float* ip = in + (size_t)row * NC;
  float v0 = ip[t], v1 = ip[t + 128], v2 = ip[t + 256];
  if (add) {
    const float* ap = add + (size_t)row * NC;
    v0 += ap[t]; v1 += ap[t + 128]; v2 += ap[t + 256];
  }
  red[t] = v0 + v1 + v2;
  __syncthreads();
  for (int o = 64; o > 0; o >>= 1) { if (t < o) red[t] += red[t + o]; __syncthreads(); }
  const float m = red[0] / (float)NC;
  __syncthreads();
  float d0 = v0 - m, d1 = v1 - m, d2 = v2 - m;
  red[t] = d0 * d0 + d1 * d1 + d2 * d2;
  __syncthreads();
  for (int o = 64; o > 0; o >>= 1) { if (t < o) red[t] += red[t + o]; __syncthreads(); }
  const float rs = rsqrtf(red[0] / (float)NC + LN_EPS);
  float* yp = y + (size_t)row * NC;
  yp[t]       = d0 * rs * g[t]       + b[t];
  yp[t + 128] = d1 * rs * g[t + 128] + b[t + 128];
  yp[t + 256] = d2 * rs * g[t + 256] + b[t + 256];
  if (xout) {
    float* xp = xout + (size_t)row * NC;
    xp[t] = v0; xp[t + 128] = v1; xp[t + 256] = v2;
  }
}

// ---------------- 10. generic fp32 GEMM: C = act(A @ W^T + bias) (+R) ----------------
template <int ACT, bool HAS_RES>
__global__ __launch_bounds__(256) void gemm_kernel(const float* __restrict__ A,
                                                   const float* __restrict__ W,
                                                   const float* __restrict__ bias,
                                                   const float* __restrict__ R,
                                                   float* __restrict__ C,
                                                   int M, int N, int Kd) {
  __shared__ float As[16][68];
  __shared__ float Ws[16][68];
  const int tid = threadIdx.x;
  const int tx = tid & 15, ty = tid >> 4;
  const int n0 = blockIdx.x * 64, m0 = blockIdx.y * 64;
  float acc[4][4] = {};
  for (int k0 = 0; k0 < Kd; k0 += 16) {
    for (int e = tid; e < 1024; e += 256) {
      const int r = e >> 4, kk = e & 15;
      As[kk][r] = A[(size_t)(m0 + r) * Kd + k0 + kk];
    }
    for (int e = tid; e < 1024; e += 256) {
      const int r = e >> 4, kk = e & 15;
      Ws[kk][r] = W[(size_t)(n0 + r) * Kd + k0 + kk];
    }
    __syncthreads();
#pragma unroll
    for (int kk = 0; kk < 16; ++kk) {
      float a0[4], b0[4];
#pragma unroll
      for (int i = 0; i < 4; ++i) a0[i] = As[kk][ty * 4 + i];
#pragma unroll
      for (int j = 0; j < 4; ++j) b0[j] = Ws[kk][tx * 4 + j];
#pragma unroll
      for (int i = 0; i < 4; ++i)
#pragma unroll
        for (int j = 0; j < 4; ++j) acc[i][j] = fmaf(a0[i], b0[j], acc[i][j]);
    }
    __syncthreads();
  }
#pragma unroll
  for (int i = 0; i < 4; ++i) {
    const int m = m0 + ty * 4 + i;
#pragma unroll
    for (int j = 0; j < 4; ++j) {
      const int n = n0 + tx * 4 + j;
      float v = acc[i][j] + bias[n];
      if (ACT == 1) v = 0.5f * v * (1.0f + erff(v * 0.70710678118654752f));
      if (HAS_RES) v += R[(size_t)m * N + n];
      C[(size_t)m * N + n] = v;
    }
  }
}

// ---------------- 11. attention ----------------
__global__ __launch_bounds__(256) void attn_scores(const float* __restrict__ qkv,
                                                   float* __restrict__ sc) {
  __shared__ float qs[32][NDH + 1];
  __shared__ float ks[NG][NDH + 1];
  const int blk = blockIdx.x, t = threadIdx.x;
  const int qt = blk & 3;
  const int h = (blk >> 2) % NH;
  const int b = blk / (4 * NH);
  for (int e = t; e < 32 * NDH; e += 256) {
    const int r = e >> 6, d = e & 63;
    qs[r][d] = qkv[((size_t)(b * NG + qt * 32 + r)) * (3 * NC) + h * NDH + d];
  }
  for (int e = t; e < NG * NDH; e += 256) {
    const int r = e >> 6, d = e & 63;
    ks[r][d] = qkv[((size_t)(b * NG + r)) * (3 * NC) + NC + h * NDH + d];
  }
  __syncthreads();
  for (int e = t; e < 32 * NG; e += 256) {
    const int r = e >> 7, kc = e & 127;
    const int qi = qt * 32 + r;
    float acc = 0.f;
#pragma unroll
    for (int d = 0; d < NDH; ++d) acc = fmaf(qs[r][d], ks[kc][d], acc);
    const float v = (kc <= qi) ? acc * 0.125f : -1e9f;
    sc[(((size_t)(b * NH + h)) * NG + qi) * NG + kc] = v;
  }
}

__global__ __launch_bounds__(128) void softmax_kernel(float* __restrict__ sc) {
  __shared__ float red[128];
  const size_t row = blockIdx.x;
  const int t = threadIdx.x;
  float v = sc[row * NG + t];
  red[t] = v;
  __syncthreads();
  for (int o = 64; o > 0; o >>= 1) { if (t < o) red[t] = fmaxf(red[t], red[t + o]); __syncthreads(); }
  const float m = red[0];
  __syncthreads();
  const float e = expf(v - m);
  red[t] = e;
  __syncthreads();
  for (int o = 64; o > 0; o >>= 1) { if (t < o) red[t] += red[t + o]; __syncthreads(); }
  sc[row * NG + t] = e / red[0];
}

__global__ __launch_bounds__(256) void attn_pv(const float* __restrict__ qkv,
                                               const float* __restrict__ sc,
                                               float* __restrict__ obuf) {
  __shared__ float ps[32][NG + 1];
  __shared__ float vs[NG][NDH + 1];
  const int blk = blockIdx.x, t = threadIdx.x;
  const int ot = blk & 3;
  const int h = (blk >> 2) % NH;
  const int b = blk / (4 * NH);
  for (int e = t; e < 32 * NG; e += 256) {
    const int r = e >> 7, kc = e & 127;
    ps[r][kc] = sc[(((size_t)(b * NH + h)) * NG + ot * 32 + r) * NG + kc];
  }
  for (int e = t; e < NG * NDH; e += 256) {
    const int r = e >> 6, d = e & 63;
    vs[r][d] = qkv[((size_t)(b * NG + r)) * (3 * NC) + 2 * NC + h * NDH + d];
  }
  __syncthreads();
  for (int e = t; e < 32 * NDH; e += 256) {
    const int r = e >> 6, d = e & 63;
    float acc = 0.f;
#pragma unroll 8
    for (int k = 0; k < NG; ++k) acc = fmaf(ps[r][k], vs[k][d], acc);
    obuf[((size_t)(b * NG + ot * 32 + r)) * NC + h * NDH + d] = acc;
  }
}

// ---------------- launch ----------------
extern "C" void kernel_launch(void* const* d_in, const int* in_sizes, int n_in,
                              void* d_out, int out_size, void* d_ws, size_t ws_size,
                              hipStream_t stream) {
  (void)in_sizes; (void)n_in; (void)out_size; (void)ws_size;
  const float* xyz  = (const float*)d_in[0];
  const float* ec1w = (const float*)d_in[1];
  const float* ec1b = (const float*)d_in[2];
  const float* bn1g = (const float*)d_in[3];
  const float* bn1b = (const float*)d_in[4];
  const float* ec2w = (const float*)d_in[5];
  const float* ec2b = (const float*)d_in[6];
  const float* sc1w = (const float*)d_in[7];
  const float* sc1b = (const float*)d_in[8];
  const float* bn2g = (const float*)d_in[9];
  const float* bn2b = (const float*)d_in[10];
  const float* sc2w = (const float*)d_in[11];
  const float* sc2b = (const float*)d_in[12];
  const float* sos  = (const float*)d_in[13];
  const float* ln1g = (const float*)d_in[14];
  const float* ln1b = (const float*)d_in[15];
  const float* qkvw = (const float*)d_in[16];
  const float* qkvb = (const float*)d_in[17];
  const float* outw = (const float*)d_in[18];
  const float* outb = (const float*)d_in[19];
  const float* ln2g = (const float*)d_in[20];
  const float* ln2b = (const float*)d_in[21];
  const float* m1w  = (const float*)d_in[22];
  const float* m1b  = (const float*)d_in[23];
  const float* m2w  = (const float*)d_in[24];
  const float* m2b  = (const float*)d_in[25];
  const float* lnfg = (const float*)d_in[26];
  const float* lnfb = (const float*)d_in[27];
  float* out = (float*)d_out;

  char* p = (char*)d_ws;
  auto carve = [&](size_t bytes) -> void* {
    void* q = (void*)p;
    p += (bytes + 255) & ~(size_t)255;
    return q;
  };
  int*   cent   = (int*)carve((size_t)NB * NG * 4);
  float* center = (float*)carve((size_t)NB * NG * 3 * 4);
  int*   knn    = (int*)carve((size_t)NB * NG * NK * 4);
  int*   order  = (int*)carve((size_t)NB * NG * 4);
  float* neigh  = (float*)carve((size_t)NB * NG * NK * 3 * 4);
  float* cord   = (float*)carve((size_t)NB * NG * 3 * 4);
  float* psum1  = (float*)carve((size_t)128 * 256 * 4);
  float* psq1   = (float*)carve((size_t)128 * 256 * 4);
  float* A1     = (float*)carve(128 * 4);
  float* B01    = (float*)carve(128 * 4);
  float* psum2  = (float*)carve((size_t)512 * 2048 * 4);
  float* psq2   = (float*)carve((size_t)512 * 2048 * 4);
  float* A2     = (float*)carve(512 * 4);
  float* B02    = (float*)carve(512 * 4);
  float* tokens = (float*)carve((size_t)NB * NG * NC * 4);
  float* posb   = (float*)carve((size_t)NB * NG * NC * 4);
  float* hbuf   = (float*)carve((size_t)NB * NG * NC * 4);
  float* xbuf   = (float*)carve((size_t)NB * NG * NC * 4);
  float* ybuf   = (float*)carve((size_t)NB * NG * NC * 4);
  float* qkvbuf = (float*)carve((size_t)NB * NG * 3 * NC * 4);
  float* scbuf  = (float*)carve((size_t)NB * NH * NG * NG * 4);
  float* obuf   = (float*)carve((size_t)NB * NG * NC * 4);
  float* mhbuf  = (float*)carve((size_t)NB * NG * NHID * 4);

  const int NTOK = NB * NG;  // 2048

  fps_kernel<<<NB, 512, 0, stream>>>(xyz, cent);
  knn_kernel<<<NTOK, 256, 0, stream>>>(xyz, cent, center, knn);
  order_kernel<<<NB, 128, 0, stream>>>(center, order);
  gather_neigh<<<NTOK, 32, 0, stream>>>(xyz, knn, order, center, neigh, cord);

  bn1_stats<<<256, 128, 0, stream>>>(neigh, ec1w, ec1b, psum1, psq1);
  bn1_reduce<<<128, 256, 0, stream>>>(psum1, psq1, bn1g, bn1b, A1, B01);
  enc_stats2b<<<NTOK, 256, SM_E2_FLOATS * 4, stream>>>(neigh, ec1w, ec1b, A1, B01,
                                                       ec2w, ec2b, sc1w, sc1b, psum2, psq2);
  bn2_reduce<<<512, 256, 0, stream>>>(psum2, psq2, bn2g, bn2b, A2, B02);
  enc_tokens2<<<NTOK, 256, SM_E3_FLOATS * 4, stream>>>(neigh, ec1w, ec1b, A1, B01, ec2w, ec2b,
                                                       sc1w, sc1b, A2, B02, sc2w, sc2b, tokens);

  pos_kernel<<<NTOK, NC, 0, stream>>>(cord, posb);
  hinit_kernel<<<NTOK, NC, 0, stream>>>(tokens, sos, hbuf);

  for (int l = 0; l < NL; ++l) {
    ln_kernel<<<NTOK, 128, 0, stream>>>(hbuf, posb, ln1g + l * NC, ln1b + l * NC, ybuf, xbuf);
    gemm_kernel<0, false><<<dim3(3 * NC / 64, NTOK / 64), 256, 0, stream>>>(
        ybuf, qkvw + (size_t)l * 3 * NC * NC, qkvb + (size_t)l * 3 * NC, nullptr, qkvbuf,
        NTOK, 3 * NC, NC);
    attn_scores<<<NB * NH * 4, 256, 0, stream>>>(qkvbuf, scbuf);
    softmax_kernel<<<NB * NH * NG, 128, 0, stream>>>(scbuf);
    attn_pv<<<NB * NH * 4, 256, 0, stream>>>(qkvbuf, scbuf, obuf);
    gemm_kernel<0, true><<<dim3(NC / 64, NTOK / 64), 256, 0, stream>>>(
        obuf, outw + (size_t)l * NC * NC, outb + (size_t)l * NC, xbuf, hbuf,
        NTOK, NC, NC);
    ln_kernel<<<NTOK, 128, 0, stream>>>(hbuf, nullptr, ln2g + l * NC, ln2b + l * NC, ybuf, nullptr);
    gemm_kernel<1, false><<<dim3(NHID / 64, NTOK / 64), 256, 0, stream>>>(
        ybuf, m1w + (size_t)l * NHID * NC, m1b + (size_t)l * NHID, nullptr, mhbuf,
        NTOK, NHID, NC);
    gemm_kernel<0, true><<<dim3(NC / 64, NTOK / 64), 256, 0, stream>>>(
        mhbuf, m2w + (size_t)l * NC * NHID, m2b + (size_t)l * NC, hbuf, hbuf,
        NTOK, NC, NHID);
  }
  ln_kernel<<<NTOK, 128, 0, stream>>>(hbuf, nullptr, lnfg, lnfb, out, nullptr);
}

// Round 7
// 4562.825 us; speedup vs baseline: 1.8356x; 1.8356x over previous
//
#include <hip/hip_runtime.h>
#include <math.h>

#define DEVFN __device__ __forceinline__

constexpr int NB   = 16;     // batch
constexpr int NPTS = 8192;   // N points
constexpr int NG   = 128;    // groups
constexpr int NK   = 32;     // knn
constexpr int NC   = 384;    // model dim
constexpr int NH   = 6;      // heads
constexpr int NL   = 12;     // layers
constexpr int NHID = 1536;   // mlp hidden
constexpr int NDH  = 64;     // head dim
constexpr float LN_EPS = 1e-5f;

typedef __attribute__((ext_vector_type(8))) short short8v;
typedef __attribute__((ext_vector_type(4))) float f32x4;

// fp32 ops without fma contraction, to track numpy's rounding in the
// index-selection stages (FPS / kNN / path ordering).
DEVFN float sq3(float x, float y, float z) {
  return __fadd_rn(__fadd_rn(__fmul_rn(x, x), __fmul_rn(y, y)), __fmul_rn(z, z));
}
DEVFN float dot3(float ax, float ay, float az, float bx, float by, float bz) {
  return __fadd_rn(__fadd_rn(__fmul_rn(ax, bx), __fmul_rn(ay, by)), __fmul_rn(az, bz));
}
DEVFN unsigned short f2bf(float f) {   // RTNE fp32 -> bf16
  unsigned u = __float_as_uint(f);
  return (unsigned short)((u + 0x7fffu + ((u >> 16) & 1u)) >> 16);
}
DEVFN float bf2f(unsigned short u) { return __uint_as_float(((unsigned)u) << 16); }

// ---------------- 1. farthest point sampling (one block per batch) ----------------
__global__ __launch_bounds__(512) void fps_kernel(const float* __restrict__ xyz,
                                                  int* __restrict__ cent) {
  __shared__ float dist[NPTS];
  __shared__ float rv[512];
  __shared__ int   ri[512];
  const int b = blockIdx.x, t = threadIdx.x;
  const float* X = xyz + (size_t)b * NPTS * 3;
  for (int i = t; i < NPTS; i += 512) dist[i] = 1e10f;
  __syncthreads();
  int far = 0;
  for (int s = 0; s < NG; ++s) {
    if (t == 0) cent[b * NG + s] = far;
    const float cx = X[far * 3 + 0], cy = X[far * 3 + 1], cz = X[far * 3 + 2];
    float bv = -1.0f; int bi = 0;
    for (int i = t; i < NPTS; i += 512) {
      float dx = __fsub_rn(X[i * 3 + 0], cx);
      float dy = __fsub_rn(X[i * 3 + 1], cy);
      float dz = __fsub_rn(X[i * 3 + 2], cz);
      float d  = sq3(dx, dy, dz);
      float nd = fminf(dist[i], d);
      dist[i] = nd;
      if (nd > bv) { bv = nd; bi = i; }   // first-occurrence within strided subset
    }
    rv[t] = bv; ri[t] = bi;
    __syncthreads();
    for (int o = 256; o > 0; o >>= 1) {
      if (t < o) {
        if (rv[t + o] > rv[t] || (rv[t + o] == rv[t] && ri[t + o] < ri[t])) {
          rv[t] = rv[t + o]; ri[t] = ri[t + o];
        }
      }
      __syncthreads();
    }
    far = ri[0];
    __syncthreads();
  }
}

// ---------------- 2. kNN (one block per (b,g) center) ----------------
__global__ __launch_bounds__(256) void knn_kernel(const float* __restrict__ xyz,
                                                  const int* __restrict__ cent,
                                                  float* __restrict__ center,
                                                  int* __restrict__ knn) {
  __shared__ float d2s[NPTS];
  __shared__ float rv[256];
  __shared__ int   ri[256];
  const int bg = blockIdx.x, t = threadIdx.x;
  const int b = bg >> 7;
  const float* X = xyz + (size_t)b * NPTS * 3;
  const int ci = cent[bg];
  const float cx = X[ci * 3 + 0], cy = X[ci * 3 + 1], cz = X[ci * 3 + 2];
  if (t == 0) { center[bg * 3 + 0] = cx; center[bg * 3 + 1] = cy; center[bg * 3 + 2] = cz; }
  const float ra = sq3(cx, cy, cz);
  for (int i = t; i < NPTS; i += 256) {
    float x = X[i * 3 + 0], y = X[i * 3 + 1], z = X[i * 3 + 2];
    float rb = sq3(x, y, z);
    float dt = dot3(cx, cy, cz, x, y, z);
    // match reference: max(0, (ra+rb) - 2*dot)
    d2s[i] = fmaxf(__fsub_rn(__fadd_rn(ra, rb), __fmul_rn(2.0f, dt)), 0.0f);
  }
  __syncthreads();
  for (int k = 0; k < NK; ++k) {
    float bv = 3.0e38f; int bi = 0;
    for (int i = t; i < NPTS; i += 256) {
      float v = d2s[i];
      if (v < bv) { bv = v; bi = i; }
    }
    rv[t] = bv; ri[t] = bi;
    __syncthreads();
    for (int o = 128; o > 0; o >>= 1) {
      if (t < o) {
        if (rv[t + o] < rv[t] || (rv[t + o] == rv[t] && ri[t + o] < ri[t])) {
          rv[t] = rv[t + o]; ri[t] = ri[t + o];
        }
      }
      __syncthreads();
    }
    if (t == 0) { knn[(size_t)bg * NK + k] = ri[0]; d2s[ri[0]] = 3.0e38f; }
    __syncthreads();
  }
}

// ---------------- 3. greedy nearest path over centers (one block per batch) ----------------
__global__ __launch_bounds__(128) void order_kernel(const float* __restrict__ center,
                                                    int* __restrict__ order) {
  __shared__ float cx[NG], cy[NG], cz[NG];
  __shared__ int   vis[NG];
  __shared__ float rv[NG];
  __shared__ int   ri[NG];
  const int b = blockIdx.x, t = threadIdx.x;
  cx[t] = center[((size_t)b * NG + t) * 3 + 0];
  cy[t] = center[((size_t)b * NG + t) * 3 + 1];
  cz[t] = center[((size_t)b * NG + t) * 3 + 2];
  vis[t] = (t == 0) ? 1 : 0;
  if (t == 0) order[b * NG] = 0;
  __syncthreads();
  int last = 0;
  for (int s = 1; s < NG; ++s) {
    float d;
    if (vis[t]) {
      d = 3.0e38f;
    } else {
      const float lx = cx[last], ly = cy[last], lz = cz[last];
      float ra = sq3(lx, ly, lz), rb = sq3(cx[t], cy[t], cz[t]);
      float dd = __fsub_rn(__fadd_rn(ra, rb), __fmul_rn(2.0f, dot3(lx, ly, lz, cx[t], cy[t], cz[t])));
      d = fmaxf(dd, 0.0f);
    }
    rv[t] = d; ri[t] = t;
    __syncthreads();
    for (int o = 64; o > 0; o >>= 1) {
      if (t < o) {
        if (rv[t + o] < rv[t] || (rv[t + o] == rv[t] && ri[t + o] < ri[t])) {
          rv[t] = rv[t + o]; ri[t] = ri[t + o];
        }
      }
      __syncthreads();
    }
    last = ri[0];
    if (t == 0) order[b * NG + s] = last;
    if (t == last) vis[t] = 1;
    __syncthreads();
  }
}

// ---------------- 4. gather ordered neighborhoods ----------------
__global__ void gather_neigh(const float* __restrict__ xyz, const int* __restrict__ knn,
                             const int* __restrict__ order, const float* __restrict__ center,
                             float* __restrict__ neigh, float* __restrict__ cord) {
  const int bg = blockIdx.x, t = threadIdx.x;  // 32 threads
  const int b = bg >> 7;
  const int src = order[bg];
  const int sbg = (b << 7) + src;
  const float c0 = center[sbg * 3 + 0], c1 = center[sbg * 3 + 1], c2 = center[sbg * 3 + 2];
  if (t < 3) cord[bg * 3 + t] = center[sbg * 3 + t];
  const int idx = knn[(size_t)sbg * NK + t];
  const float* P = xyz + ((size_t)b * NPTS + idx) * 3;
  float* o = neigh + ((size_t)bg * NK + t) * 3;
  o[0] = __fsub_rn(P[0], c0);
  o[1] = __fsub_rn(P[1], c1);
  o[2] = __fsub_rn(P[2], c2);
}

// ---------------- 5. encoder: BN1 statistics ----------------
__global__ __launch_bounds__(128) void bn1_stats(const float* __restrict__ neigh,
                                                 const float* __restrict__ w,
                                                 const float* __restrict__ bias,
                                                 float* __restrict__ psum,
                                                 float* __restrict__ psq) {
  const int c = threadIdx.x, blk = blockIdx.x;   // 256 blocks x 128 ch
  const float wx = w[c * 3 + 0], wy = w[c * 3 + 1], wz = w[c * 3 + 2], bb = bias[c];
  float s = 0.f, s2 = 0.f;
  const float* nr = neigh + (size_t)blk * 256 * 3;
  for (int r = 0; r < 256; ++r) {
    float y = fmaf(nr[r * 3 + 2], wz, fmaf(nr[r * 3 + 1], wy, fmaf(nr[r * 3 + 0], wx, bb)));
    s += y; s2 = fmaf(y, y, s2);
  }
  psum[c * 256 + blk] = s;
  psq[c * 256 + blk]  = s2;
}

__global__ __launch_bounds__(256) void bn1_reduce(const float* __restrict__ psum,
                                                  const float* __restrict__ psq,
                                                  const float* __restrict__ g,
                                                  const float* __restrict__ b,
                                                  float* __restrict__ A, float* __restrict__ B0) {
  __shared__ double rs[256], rq[256];
  const int c = blockIdx.x, t = threadIdx.x;
  rs[t] = (double)psum[c * 256 + t];
  rq[t] = (double)psq[c * 256 + t];
  __syncthreads();
  for (int o = 128; o > 0; o >>= 1) {
    if (t < o) { rs[t] += rs[t + o]; rq[t] += rq[t + o]; }
    __syncthreads();
  }
  if (t == 0) {
    const double M = 65536.0;
    double m = rs[0] / M;
    double v = rq[0] / M - m * m;
    if (v < 0) v = 0;
    float a = g[c] * rsqrtf((float)v + LN_EPS);
    A[c] = a;
    B0[c] = b[c] - (float)m * a;
  }
}

// ---------------- encoder shared-memory layout (dynamic LDS) ----------------
// floats: ns[128] | gm[256] | f2[32*256] | ubuf[4224] (f1 32x128 | W3t 32x132 | w4t 8x388)
//         | stile[32*128]
constexpr int SM_NS    = 0;
constexpr int SM_GM    = 128;
constexpr int SM_F2    = 384;
constexpr int SM_UBUF  = 384 + 32 * 256;           // 8576
constexpr int SM_STILE = SM_UBUF + 32 * 132;       // 12800
constexpr int SM_ENC_FLOATS = SM_STILE + 32 * 128; // 16896 -> 67584 B (2 blocks/CU)

// phase A: f1 = relu(bn1(neigh@ec1w^T)) ; f2 = f1@ec2w^T + ec2b ; gm = colmax(f2)
__device__ __forceinline__ void enc_phaseA(int bg, int t, const float* __restrict__ neigh,
                                           const float* __restrict__ ec1w, const float* __restrict__ ec1b,
                                           const float* __restrict__ A1, const float* __restrict__ B01,
                                           const float* __restrict__ ec2w, const float* __restrict__ ec2b,
                                           float* ns, float* f1 /*32x128*/, float* f2 /*32x256*/, float* gm) {
  if (t < 96) ns[t] = neigh[(size_t)bg * 96 + t];
  __syncthreads();
  for (int e = t; e < 32 * 128; e += 256) {
    const int r = e >> 7, c = e & 127;
    float y = fmaf(ns[r * 3 + 2], ec1w[c * 3 + 2],
             fmaf(ns[r * 3 + 1], ec1w[c * 3 + 1],
             fmaf(ns[r * 3 + 0], ec1w[c * 3 + 0], ec1b[c])));
    y = fmaf(y, A1[c], B01[c]);
    f1[r * 128 + c] = fmaxf(y, 0.f);
  }
  __syncthreads();
  {
    const int c = t;   // one output column per thread
    float acc[32];
#pragma unroll
    for (int r = 0; r < 32; ++r) acc[r] = ec2b[c];
    const float4* wr = (const float4*)(ec2w + (size_t)c * 128);
    for (int j = 0; j < 32; ++j) {
      const float4 wv = wr[j];
#pragma unroll
      for (int r = 0; r < 32; ++r) {
        const float4 fv = *(const float4*)&f1[r * 128 + j * 4];
        acc[r] = fmaf(fv.w, wv.w, fmaf(fv.z, wv.z, fmaf(fv.y, wv.y, fmaf(fv.x, wv.x, acc[r]))));
      }
    }
    float m = -3.0e38f;
#pragma unroll
    for (int r = 0; r < 32; ++r) { f2[r * 256 + c] = acc[r]; m = fmaxf(m, acc[r]); }
    gm[c] = m;
  }
  __syncthreads();
}

// mm3 for one 128-column tile: stile = x3 @ sc1w^T + sc1b (x3 = [gm | f2])
// gm part is row-constant -> computed once per column (acc0), then replicated.
__device__ __forceinline__ void mm3_tile(int n3, int t,
                                         const float* __restrict__ sc1w, const float* __restrict__ sc1b,
                                         const float* gm, const float* f2,
                                         float* w3t /*32x132*/, float* stile /*32x128*/) {
  const int rx = t >> 5, cx = t & 31;
  float acc0[4] = {0.f, 0.f, 0.f, 0.f};
  float acc[4][4];
  for (int k3 = 0; k3 < 16; ++k3) {
    // stage W3t[kk][c] <- sc1w[n3*128+c][k3*32+kk]
    for (int idx = t; idx < 1024; idx += 256) {
      const int c = idx >> 3, j = idx & 7;
      const float4 wv = *(const float4*)(sc1w + (size_t)(n3 * 128 + c) * 512 + k3 * 32 + j * 4);
      w3t[(j * 4 + 0) * 132 + c] = wv.x;
      w3t[(j * 4 + 1) * 132 + c] = wv.y;
      w3t[(j * 4 + 2) * 132 + c] = wv.z;
      w3t[(j * 4 + 3) * 132 + c] = wv.w;
    }
    __syncthreads();
    if (k3 == 8) {
#pragma unroll
      for (int j = 0; j < 4; ++j) {
        acc[0][j] = acc0[j]; acc[1][j] = acc0[j]; acc[2][j] = acc0[j]; acc[3][j] = acc0[j];
      }
    }
    if (k3 < 8) {
#pragma unroll
      for (int kk = 0; kk < 32; ++kk) {
        const float a = gm[k3 * 32 + kk];
        const float4 w = *(const float4*)(w3t + kk * 132 + cx * 4);
        acc0[0] = fmaf(a, w.x, acc0[0]); acc0[1] = fmaf(a, w.y, acc0[1]);
        acc0[2] = fmaf(a, w.z, acc0[2]); acc0[3] = fmaf(a, w.w, acc0[3]);
      }
    } else {
#pragma unroll
      for (int kk = 0; kk < 32; ++kk) {
        const float4 w = *(const float4*)(w3t + kk * 132 + cx * 4);
#pragma unroll
        for (int i = 0; i < 4; ++i) {
          const float a = f2[(rx * 4 + i) * 256 + k3 * 32 + kk - 256];
          acc[i][0] = fmaf(a, w.x, acc[i][0]); acc[i][1] = fmaf(a, w.y, acc[i][1]);
          acc[i][2] = fmaf(a, w.z, acc[i][2]); acc[i][3] = fmaf(a, w.w, acc[i][3]);
        }
      }
    }
    __syncthreads();
  }
#pragma unroll
  for (int i = 0; i < 4; ++i)
#pragma unroll
    for (int j = 0; j < 4; ++j)
      stile[(rx * 4 + i) * 128 + cx * 4 + j] = acc[i][j] + sc1b[n3 * 128 + cx * 4 + j];
}

// mm4 accumulation for one 128-k slice (the n3-th mm3 tile, post bn2+relu in stile)
__device__ __forceinline__ void mm4_acc(int n3, int t, const float* __restrict__ sc2w,
                                        const float* stile, float* w4t /*8x388*/,
                                        float acc4[4][12]) {
  const int rx = t >> 5, cy = t & 31;
  for (int ks = 0; ks < 16; ++ks) {
    for (int idx = t; idx < 768; idx += 256) {
      const int n = idx >> 1, h = idx & 1;
      const float4 wv = *(const float4*)(sc2w + (size_t)n * 512 + n3 * 128 + ks * 8 + h * 4);
      w4t[(h * 4 + 0) * 388 + n] = wv.x;
      w4t[(h * 4 + 1) * 388 + n] = wv.y;
      w4t[(h * 4 + 2) * 388 + n] = wv.z;
      w4t[(h * 4 + 3) * 388 + n] = wv.w;
    }
    __syncthreads();
#pragma unroll
    for (int kk = 0; kk < 8; ++kk) {
      float a[4];
#pragma unroll
      for (int i = 0; i < 4; ++i) a[i] = stile[(rx * 4 + i) * 128 + ks * 8 + kk];
#pragma unroll
      for (int j4 = 0; j4 < 3; ++j4) {
        const float4 w = *(const float4*)(w4t + kk * 388 + cy * 12 + j4 * 4);
#pragma unroll
        for (int i = 0; i < 4; ++i) {
          acc4[i][j4 * 4 + 0] = fmaf(a[i], w.x, acc4[i][j4 * 4 + 0]);
          acc4[i][j4 * 4 + 1] = fmaf(a[i], w.y, acc4[i][j4 * 4 + 1]);
          acc4[i][j4 * 4 + 2] = fmaf(a[i], w.z, acc4[i][j4 * 4 + 2]);
          acc4[i][j4 * 4 + 3] = fmaf(a[i], w.w, acc4[i][j4 * 4 + 3]);
        }
      }
    }
    __syncthreads();
  }
}

// ---------------- 6. encoder: BN2 statistics ----------------
__global__ __launch_bounds__(256) void enc_stats2b(const float* __restrict__ neigh,
                                                   const float* __restrict__ ec1w, const float* __restrict__ ec1b,
                                                   const float* __restrict__ A1, const float* __restrict__ B01,
                                                   const float* __restrict__ ec2w, const float* __restrict__ ec2b,
                                                   const float* __restrict__ sc1w, const float* __restrict__ sc1b,
                                                   float* __restrict__ psum, float* __restrict__ psq) {
  extern __shared__ float sm[];
  float* ns = sm + SM_NS; float* gm = sm + SM_GM; float* f2 = sm + SM_F2;
  float* ubuf = sm + SM_UBUF; float* stile = sm + SM_STILE;
  const int bg = blockIdx.x, t = threadIdx.x;
  enc_phaseA(bg, t, neigh, ec1w, ec1b, A1, B01, ec2w, ec2b, ns, ubuf, f2, gm);
  for (int n3 = 0; n3 < 4; ++n3) {
    mm3_tile(n3, t, sc1w, sc1b, gm, f2, ubuf, stile);
    __syncthreads();
    if (t < 128) {
      const int cg = n3 * 128 + t;
      float s = 0.f, q = 0.f;
      for (int r = 0; r < 32; ++r) {
        const float v = stile[r * 128 + t];
        s += v; q = fmaf(v, v, q);
      }
      psum[(size_t)cg * 2048 + bg] = s;
      psq[(size_t)cg * 2048 + bg]  = q;
    }
    __syncthreads();
  }
}

__global__ __launch_bounds__(256) void bn2_reduce(const float* __restrict__ psum,
                                                  const float* __restrict__ psq,
                                                  const float* __restrict__ g,
                                                  const float* __restrict__ b,
                                                  float* __restrict__ A, float* __restrict__ B0) {
  __shared__ double rs[256], rq[256];
  const int c = blockIdx.x, t = threadIdx.x;
  double s = 0.0, q = 0.0;
  for (int i = t; i < 2048; i += 256) {
    s += (double)psum[(size_t)c * 2048 + i];
    q += (double)psq[(size_t)c * 2048 + i];
  }
  rs[t] = s; rq[t] = q;
  __syncthreads();
  for (int o = 128; o > 0; o >>= 1) {
    if (t < o) { rs[t] += rs[t + o]; rq[t] += rq[t + o]; }
    __syncthreads();
  }
  if (t == 0) {
    const double M = 65536.0;
    double m = rs[0] / M;
    double v = rq[0] / M - m * m;
    if (v < 0) v = 0;
    float a = g[c] * rsqrtf((float)v + LN_EPS);
    A[c] = a;
    B0[c] = b[c] - (float)m * a;
  }
}

// ---------------- 7. encoder: tokens ----------------
__global__ __launch_bounds__(256) void enc_tokens2(const float* __restrict__ neigh,
                                                   const float* __restrict__ ec1w, const float* __restrict__ ec1b,
                                                   const float* __restrict__ A1, const float* __restrict__ B01,
                                                   const float* __restrict__ ec2w, const float* __restrict__ ec2b,
                                                   const float* __restrict__ sc1w, const float* __restrict__ sc1b,
                                                   const float* __restrict__ A2, const float* __restrict__ B02,
                                                   const float* __restrict__ sc2w, const float* __restrict__ sc2b,
                                                   float* __restrict__ tokens) {
  extern __shared__ float sm[];
  float* ns = sm + SM_NS; float* gm = sm + SM_GM; float* f2 = sm + SM_F2;
  float* ubuf = sm + SM_UBUF; float* stile = sm + SM_STILE;
  float* w4t = ubuf;   // alias: w3t staging and w4t staging never live simultaneously
  const int bg = blockIdx.x, t = threadIdx.x;
  enc_phaseA(bg, t, neigh, ec1w, ec1b, A1, B01, ec2w, ec2b, ns, ubuf, f2, gm);
  float acc4[4][12] = {};
  for (int n3 = 0; n3 < 4; ++n3) {
    mm3_tile(n3, t, sc1w, sc1b, gm, f2, ubuf, stile);
    __syncthreads();
    for (int e = t; e < 32 * 128; e += 256) {
      const int r = e >> 7, c = e & 127, cg = n3 * 128 + c;
      stile[r * 128 + c] = fmaxf(fmaf(stile[r * 128 + c], A2[cg], B02[cg]), 0.f);
    }
    __syncthreads();
    mm4_acc(n3, t, sc2w, stile, w4t, acc4);
  }
  // maxpool over the 32 rows: thread-local over its 4 rows, then across 8 row-groups
  const int rx = t >> 5, cy = t & 31;
  float* tk = stile;   // reuse (needs 8*384 <= 4096)
  __syncthreads();
#pragma unroll
  for (int j = 0; j < 12; ++j) {
    const float m = fmaxf(fmaxf(acc4[0][j], acc4[1][j]), fmaxf(acc4[2][j], acc4[3][j]));
    tk[rx * 384 + cy * 12 + j] = m;
  }
  __syncthreads();
  for (int c = t; c < NC; c += 256) {
    float m = tk[c];
#pragma unroll
    for (int r = 1; r < 8; ++r) m = fmaxf(m, tk[r * 384 + c]);
    tokens[(size_t)bg * NC + c] = m + sc2b[c];
  }
}

// ---------------- 8. positional embedding + h init ----------------
__global__ void pos_kernel(const float* __restrict__ cord, float* __restrict__ pos) {
  const int tok = blockIdx.x, t = threadIdx.x;   // 384 threads
  const int c = t >> 7;
  const int rem = t & 127;
  const int i = rem >> 1;
  const int isc = rem & 1;
  const float coord = cord[tok * 3 + c];
  const float ex = 2.0f * (float)i / 128.0f;
  const float inv = 1.0f / powf(10000.0f, ex);
  const float ang = coord * inv;
  pos[(size_t)tok * NC + t] = isc ? cosf(ang) : sinf(ang);
}

__global__ void hinit_kernel(const float* __restrict__ tokens, const float* __restrict__ sos,
                             float* __restrict__ h) {
  const int tok = blockIdx.x, t = threadIdx.x;   // 384 threads
  const int b = tok >> 7, g = tok & 127;
  const float v = (g == 0) ? sos[t] : tokens[((size_t)b * NG + (g - 1)) * NC + t];
  h[(size_t)tok * NC + t] = v;
}

// ---------------- weight fp32 -> bf16 conversion ----------------
__global__ void cvt_bf16(const float* __restrict__ src, unsigned short* __restrict__ dst, int n) {
  for (int i = blockIdx.x * blockDim.x + threadIdx.x; i < n; i += gridDim.x * blockDim.x)
    dst[i] = f2bf(src[i]);
}

// ---------------- 9. layernorm (optionally add first; y fp32 or bf16; optional x copy) ----------------
template <bool BF16OUT>
__global__ __launch_bounds__(128) void ln_kernel(const float* __restrict__ in,
                                                 const float* __restrict__ add,
                                                 const float* __restrict__ g,
                                                 const float* __restrict__ b,
                                                 void* __restrict__ y,
                                                 float* __restrict__ xout) {
  __shared__ float red[128];
  const int row = blockIdx.x, t = threadIdx.x;
  const float* ip = in + (size_t)row * NC;
  float v0 = ip[t], v1 = ip[t + 128], v2 = ip[t + 256];
  if (add) {
    const float* ap = add + (size_t)row * NC;
    v0 += ap[t]; v1 += ap[t + 128]; v2 += ap[t + 256];
  }
  red[t] = v0 + v1 + v2;
  __syncthreads();
  for (int o = 64; o > 0; o >>= 1) { if (t < o) red[t] += red[t + o]; __syncthreads(); }
  const float m = red[0] / (float)NC;
  __syncthreads();
  float d0 = v0 - m, d1 = v1 - m, d2 = v2 - m;
  red[t] = d0 * d0 + d1 * d1 + d2 * d2;
  __syncthreads();
  for (int o = 64; o > 0; o >>= 1) { if (t < o) red[t] += red[t + o]; __syncthreads(); }
  const float rs = rsqrtf(red[0] / (float)NC + LN_EPS);
  const float y0 = d0 * rs * g[t] + b[t];
  const float y1 = d1 * rs * g[t + 128] + b[t + 128];
  const float y2 = d2 * rs * g[t + 256] + b[t + 256];
  if (BF16OUT) {
    unsigned short* yp = (unsigned short*)y + (size_t)row * NC;
    yp[t] = f2bf(y0); yp[t + 128] = f2bf(y1); yp[t + 256] = f2bf(y2);
  } else {
    float* yp = (float*)y + (size_t)row * NC;
    yp[t] = y0; yp[t + 128] = y1; yp[t + 256] = y2;
  }
  if (xout) {
    float* xp = xout + (size_t)row * NC;
    xp[t] = v0; xp[t + 128] = v1; xp[t + 256] = v2;
  }
}

// ---------------- 10. bf16 MFMA GEMM: C = act(A @ W^T + bias) (+R) ----------------
// A: [M][K] bf16 row-major; W: [N][K] bf16 row-major. 64x64 block tile, 4 waves
// at 32x32 (2x2 fragments of 16x16x32). Fragments loaded direct from global
// (operands are L2-resident). acc fp32.
template <int ACT, bool HAS_RES, bool OUT_BF>
__global__ __launch_bounds__(256) void gemm_mfma(const unsigned short* __restrict__ A,
                                                 const unsigned short* __restrict__ W,
                                                 const float* __restrict__ bias,
                                                 const float* __restrict__ R,
                                                 void* __restrict__ Cv,
                                                 int N, int K) {
  const int t = threadIdx.x;
  const int lane = t & 63, wid = t >> 6;
  const int wr = wid >> 1, wc = wid & 1;
  const int m0 = blockIdx.y * 64 + wr * 32;
  const int n0 = blockIdx.x * 64 + wc * 32;
  const int lr = lane & 15, kg = lane >> 4;
  // A frag: row = m0 + i*16 + lr, k = k0 + kg*8 + j  (16B contiguous load)
  // B frag: col(n) = n0 + j*16 + lr, same k pattern (W row-major over k)
  const unsigned short* a0p = A + (size_t)(m0 + lr) * K + kg * 8;
  const unsigned short* a1p = a0p + (size_t)16 * K;
  const unsigned short* b0p = W + (size_t)(n0 + lr) * K + kg * 8;
  const unsigned short* b1p = b0p + (size_t)16 * K;
  f32x4 acc00 = {0.f, 0.f, 0.f, 0.f}, acc01 = acc00, acc10 = acc00, acc11 = acc00;
  for (int k0 = 0; k0 < K; k0 += 32) {
    const short8v av0 = *(const short8v*)(a0p + k0);
    const short8v av1 = *(const short8v*)(a1p + k0);
    const short8v bv0 = *(const short8v*)(b0p + k0);
    const short8v bv1 = *(const short8v*)(b1p + k0);
    acc00 = __builtin_amdgcn_mfma_f32_16x16x32_bf16(av0, bv0, acc00, 0, 0, 0);
    acc01 = __builtin_amdgcn_mfma_f32_16x16x32_bf16(av0, bv1, acc01, 0, 0, 0);
    acc10 = __builtin_amdgcn_mfma_f32_16x16x32_bf16(av1, bv0, acc10, 0, 0, 0);
    acc11 = __builtin_amdgcn_mfma_f32_16x16x32_bf16(av1, bv1, acc11, 0, 0, 0);
  }
  // epilogue: D lane map (verified m89): col = lane&15, row = (lane>>4)*4 + reg
#pragma unroll
  for (int i = 0; i < 2; ++i) {
#pragma unroll
    for (int j = 0; j < 2; ++j) {
      const f32x4 a = (i == 0) ? (j == 0 ? acc00 : acc01) : (j == 0 ? acc10 : acc11);
      const int n = n0 + j * 16 + lr;
      const float bn = bias[n];
#pragma unroll
      for (int r = 0; r < 4; ++r) {
        const int m = m0 + i * 16 + kg * 4 + r;
        float v = a[r] + bn;
        if (ACT == 1) v = 0.5f * v * (1.0f + erff(v * 0.70710678118654752f));
        if (HAS_RES) v += R[(size_t)m * N + n];
        if (OUT_BF) ((unsigned short*)Cv)[(size_t)m * N + n] = f2bf(v);
        else        ((float*)Cv)[(size_t)m * N + n] = v;
      }
    }
  }
}

// ---------------- 11. attention (bf16 qkv, fp32 scores/softmax) ----------------
__global__ __launch_bounds__(256) void attn_scores(const unsigned short* __restrict__ qkv,
                                                   float* __restrict__ sc) {
  __shared__ float qs[32][NDH + 1];
  __shared__ float ks[NG][NDH + 1];
  const int blk = blockIdx.x, t = threadIdx.x;
  const int qt = blk & 3;
  const int h = (blk >> 2) % NH;
  const int b = blk / (4 * NH);
  for (int e = t; e < 32 * NDH; e += 256) {
    const int r = e >> 6, d = e & 63;
    qs[r][d] = bf2f(qkv[((size_t)(b * NG + qt * 32 + r)) * (3 * NC) + h * NDH + d]);
  }
  for (int e = t; e < NG * NDH; e += 256) {
    const int r = e >> 6, d = e & 63;
    ks[r][d] = bf2f(qkv[((size_t)(b * NG + r)) * (3 * NC) + NC + h * NDH + d]);
  }
  __syncthreads();
  for (int e = t; e < 32 * NG; e += 256) {
    const int r = e >> 7, kc = e & 127;
    const int qi = qt * 32 + r;
    float acc = 0.f;
#pragma unroll
    for (int d = 0; d < NDH; ++d) acc = fmaf(qs[r][d], ks[kc][d], acc);
    const float v = (kc <= qi) ? acc * 0.125f : -1e9f;
    sc[(((size_t)(b * NH + h)) * NG + qi) * NG + kc] = v;
  }
}

__global__ __launch_bounds__(128) void softmax_kernel(float* __restrict__ sc) {
  __shared__ float red[128];
  const size_t row = blockIdx.x;
  const int t = threadIdx.x;
  float v = sc[row * NG + t];
  red[t] = v;
  __syncthreads();
  for (int o = 64; o > 0; o >>= 1) { if (t < o) red[t] = fmaxf(red[t], red[t + o]); __syncthreads(); }
  const float m = red[0];
  __syncthreads();
  const float e = expf(v - m);
  red[t] = e;
  __syncthreads();
  for (int o = 64; o > 0; o >>= 1) { if (t < o) red[t] += red[t + o]; __syncthreads(); }
  sc[row * NG + t] = e / red[0];
}

__global__ __launch_bounds__(256) void attn_pv(const unsigned short* __restrict__ qkv,
                                               const float* __restrict__ sc,
                                               unsigned short* __restrict__ obuf) {
  __shared__ float ps[32][NG + 1];
  __shared__ float vs[NG][NDH + 1];
  const int blk = blockIdx.x, t = threadIdx.x;
  const int ot = blk & 3;
  const int h = (blk >> 2) % NH;
  const int b = blk / (4 * NH);
  for (int e = t; e < 32 * NG; e += 256) {
    const int r = e >> 7, kc = e & 127;
    ps[r][kc] = sc[(((size_t)(b * NH + h)) * NG + ot * 32 + r) * NG + kc];
  }
  for (int e = t; e < NG * NDH; e += 256) {
    const int r = e >> 6, d = e & 63;
    vs[r][d] = bf2f(qkv[((size_t)(b * NG + r)) * (3 * NC) + 2 * NC + h * NDH + d]);
  }
  __syncthreads();
  for (int e = t; e < 32 * NDH; e += 256) {
    const int r = e >> 6, d = e & 63;
    float acc = 0.f;
#pragma unroll 8
    for (int k = 0; k < NG; ++k) acc = fmaf(ps[r][k], vs[k][d], acc);
    obuf[((size_t)(b * NG + ot * 32 + r)) * NC + h * NDH + d] = f2bf(acc);
  }
}

// ---------------- launch ----------------
extern "C" void kernel_launch(void* const* d_in, const int* in_sizes, int n_in,
                              void* d_out, int out_size, void* d_ws, size_t ws_size,
                              hipStream_t stream) {
  (void)in_sizes; (void)n_in; (void)out_size; (void)ws_size;
  const float* xyz  = (const float*)d_in[0];
  const float* ec1w = (const float*)d_in[1];
  const float* ec1b = (const float*)d_in[2];
  const float* bn1g = (const float*)d_in[3];
  const float* bn1b = (const float*)d_in[4];
  const float* ec2w = (const float*)d_in[5];
  const float* ec2b = (const float*)d_in[6];
  const float* sc1w = (const float*)d_in[7];
  const float* sc1b = (const float*)d_in[8];
  const float* bn2g = (const float*)d_in[9];
  const float* bn2b = (const float*)d_in[10];
  const float* sc2w = (const float*)d_in[11];
  const float* sc2b = (const float*)d_in[12];
  const float* sos  = (const float*)d_in[13];
  const float* ln1g = (const float*)d_in[14];
  const float* ln1b = (const float*)d_in[15];
  const float* qkvw = (const float*)d_in[16];
  const float* qkvb = (const float*)d_in[17];
  const float* outw = (const float*)d_in[18];
  const float* outb = (const float*)d_in[19];
  const float* ln2g = (const float*)d_in[20];
  const float* ln2b = (const float*)d_in[21];
  const float* m1w  = (const float*)d_in[22];
  const float* m1b  = (const float*)d_in[23];
  const float* m2w  = (const float*)d_in[24];
  const float* m2b  = (const float*)d_in[25];
  const float* lnfg = (const float*)d_in[26];
  const float* lnfb = (const float*)d_in[27];
  float* out = (float*)d_out;

  char* p = (char*)d_ws;
  auto carve = [&](size_t bytes) -> void* {
    void* q = (void*)p;
    p += (bytes + 255) & ~(size_t)255;
    return q;
  };
  int*   cent   = (int*)carve((size_t)NB * NG * 4);
  float* center = (float*)carve((size_t)NB * NG * 3 * 4);
  int*   knn    = (int*)carve((size_t)NB * NG * NK * 4);
  int*   order  = (int*)carve((size_t)NB * NG * 4);
  float* neigh  = (float*)carve((size_t)NB * NG * NK * 3 * 4);
  float* cord   = (float*)carve((size_t)NB * NG * 3 * 4);
  float* psum1  = (float*)carve((size_t)128 * 256 * 4);
  float* psq1   = (float*)carve((size_t)128 * 256 * 4);
  float* A1     = (float*)carve(128 * 4);
  float* B01    = (float*)carve(128 * 4);
  float* psum2  = (float*)carve((size_t)512 * 2048 * 4);
  float* psq2   = (float*)carve((size_t)512 * 2048 * 4);
  float* A2     = (float*)carve(512 * 4);
  float* B02    = (float*)carve(512 * 4);
  float* tokens = (float*)carve((size_t)NB * NG * NC * 4);
  float* posb   = (float*)carve((size_t)NB * NG * NC * 4);
  float* hbuf   = (float*)carve((size_t)NB * NG * NC * 4);
  float* xbuf   = (float*)carve((size_t)NB * NG * NC * 4);
  float* scbuf  = (float*)carve((size_t)NB * NH * NG * NG * 4);
  unsigned short* ybf    = (unsigned short*)carve((size_t)NB * NG * NC * 2);
  unsigned short* qkv_bf = (unsigned short*)carve((size_t)NB * NG * 3 * NC * 2);
  unsigned short* obf    = (unsigned short*)carve((size_t)NB * NG * NC * 2);
  unsigned short* mh_bf  = (unsigned short*)carve((size_t)NB * NG * NHID * 2);
  unsigned short* wqkv_bf = (unsigned short*)carve((size_t)NL * 3 * NC * NC * 2);
  unsigned short* wout_bf = (unsigned short*)carve((size_t)NL * NC * NC * 2);
  unsigned short* wm1_bf  = (unsigned short*)carve((size_t)NL * NHID * NC * 2);
  unsigned short* wm2_bf  = (unsigned short*)carve((size_t)NL * NC * NHID * 2);

  const int NTOK = NB * NG;  // 2048

  // weight conversion (deterministic, every call)
  cvt_bf16<<<2048, 256, 0, stream>>>(qkvw, wqkv_bf, NL * 3 * NC * NC);
  cvt_bf16<<<2048, 256, 0, stream>>>(outw, wout_bf, NL * NC * NC);
  cvt_bf16<<<2048, 256, 0, stream>>>(m1w, wm1_bf, NL * NHID * NC);
  cvt_bf16<<<2048, 256, 0, stream>>>(m2w, wm2_bf, NL * NC * NHID);

  fps_kernel<<<NB, 512, 0, stream>>>(xyz, cent);
  knn_kernel<<<NTOK, 256, 0, stream>>>(xyz, cent, center, knn);
  order_kernel<<<NB, 128, 0, stream>>>(center, order);
  gather_neigh<<<NTOK, 32, 0, stream>>>(xyz, knn, order, center, neigh, cord);

  bn1_stats<<<256, 128, 0, stream>>>(neigh, ec1w, ec1b, psum1, psq1);
  bn1_reduce<<<128, 256, 0, stream>>>(psum1, psq1, bn1g, bn1b, A1, B01);
  enc_stats2b<<<NTOK, 256, SM_ENC_FLOATS * 4, stream>>>(neigh, ec1w, ec1b, A1, B01,
                                                        ec2w, ec2b, sc1w, sc1b, psum2, psq2);
  bn2_reduce<<<512, 256, 0, stream>>>(psum2, psq2, bn2g, bn2b, A2, B02);
  enc_tokens2<<<NTOK, 256, SM_ENC_FLOATS * 4, stream>>>(neigh, ec1w, ec1b, A1, B01, ec2w, ec2b,
                                                        sc1w, sc1b, A2, B02, sc2w, sc2b, tokens);

  pos_kernel<<<NTOK, NC, 0, stream>>>(cord, posb);
  hinit_kernel<<<NTOK, NC, 0, stream>>>(tokens, sos, hbuf);

  for (int l = 0; l < NL; ++l) {
    ln_kernel<true><<<NTOK, 128, 0, stream>>>(hbuf, posb, ln1g + l * NC, ln1b + l * NC, ybf, xbuf);
    gemm_mfma<0, false, true><<<dim3(18, 32), 256, 0, stream>>>(
        ybf, wqkv_bf + (size_t)l * 3 * NC * NC, qkvb + (size_t)l * 3 * NC, nullptr, qkv_bf,
        3 * NC, NC);
    attn_scores<<<NB * NH * 4, 256, 0, stream>>>(qkv_bf, scbuf);
    softmax_kernel<<<NB * NH * NG, 128, 0, stream>>>(scbuf);
    attn_pv<<<NB * NH * 4, 256, 0, stream>>>(qkv_bf, scbuf, obf);
    gemm_mfma<0, true, false><<<dim3(6, 32), 256, 0, stream>>>(
        obf, wout_bf + (size_t)l * NC * NC, outb + (size_t)l * NC, xbuf, hbuf,
        NC, NC);
    ln_kernel<true><<<NTOK, 128, 0, stream>>>(hbuf, nullptr, ln2g + l * NC, ln2b + l * NC, ybf, nullptr);
    gemm_mfma<1, false, true><<<dim3(24, 32), 256, 0, stream>>>(
        ybf, wm1_bf + (size_t)l * NHID * NC, m1b + (size_t)l * NHID, nullptr, mh_bf,
        NHID, NC);
    gemm_mfma<0, true, false><<<dim3(6, 32), 256, 0, stream>>>(
        mh_bf, wm2_bf + (size_t)l * NC * NHID, m2b + (size_t)l * NC, hbuf, hbuf,
        NC, NHID);
  }
  ln_kernel<false><<<NTOK, 128, 0, stream>>>(hbuf, nullptr, lnfg, lnfb, out, nullptr);
}

// Round 8
// 2870.709 us; speedup vs baseline: 2.9176x; 1.5894x over previous
//
#include <hip/hip_runtime.h>
#include <math.h>

#define DEVFN __device__ __forceinline__

constexpr int NB   = 16;     // batch
constexpr int NPTS = 8192;   // N points
constexpr int NG   = 128;    // groups
constexpr int NK   = 32;     // knn
constexpr int NC   = 384;    // model dim
constexpr int NH   = 6;      // heads
constexpr int NL   = 12;     // layers
constexpr int NHID = 1536;   // mlp hidden
constexpr int NDH  = 64;     // head dim
constexpr float LN_EPS = 1e-5f;

typedef __attribute__((ext_vector_type(8))) short short8v;
typedef __attribute__((ext_vector_type(4))) float f32x4;

// fp32 ops without fma contraction, to track numpy's rounding in the
// index-selection stages (FPS / kNN / path ordering).
DEVFN float sq3(float x, float y, float z) {
  return __fadd_rn(__fadd_rn(__fmul_rn(x, x), __fmul_rn(y, y)), __fmul_rn(z, z));
}
DEVFN float dot3(float ax, float ay, float az, float bx, float by, float bz) {
  return __fadd_rn(__fadd_rn(__fmul_rn(ax, bx), __fmul_rn(ay, by)), __fmul_rn(az, bz));
}
DEVFN unsigned short f2bf(float f) {   // RTNE fp32 -> bf16
  unsigned u = __float_as_uint(f);
  return (unsigned short)((u + 0x7fffu + ((u >> 16) & 1u)) >> 16);
}
DEVFN float bf2f(unsigned short u) { return __uint_as_float(((unsigned)u) << 16); }

// ---------------- 1. farthest point sampling (one block per batch) ----------------
__global__ __launch_bounds__(512) void fps_kernel(const float* __restrict__ xyz,
                                                  int* __restrict__ cent) {
  __shared__ float dist[NPTS];
  __shared__ float rv[512];
  __shared__ int   ri[512];
  const int b = blockIdx.x, t = threadIdx.x;
  const float* X = xyz + (size_t)b * NPTS * 3;
  for (int i = t; i < NPTS; i += 512) dist[i] = 1e10f;
  __syncthreads();
  int far = 0;
  for (int s = 0; s < NG; ++s) {
    if (t == 0) cent[b * NG + s] = far;
    const float cx = X[far * 3 + 0], cy = X[far * 3 + 1], cz = X[far * 3 + 2];
    float bv = -1.0f; int bi = 0;
    for (int i = t; i < NPTS; i += 512) {
      float dx = __fsub_rn(X[i * 3 + 0], cx);
      float dy = __fsub_rn(X[i * 3 + 1], cy);
      float dz = __fsub_rn(X[i * 3 + 2], cz);
      float d  = sq3(dx, dy, dz);
      float nd = fminf(dist[i], d);
      dist[i] = nd;
      if (nd > bv) { bv = nd; bi = i; }   // first-occurrence within strided subset
    }
    rv[t] = bv; ri[t] = bi;
    __syncthreads();
    for (int o = 256; o > 0; o >>= 1) {
      if (t < o) {
        if (rv[t + o] > rv[t] || (rv[t + o] == rv[t] && ri[t + o] < ri[t])) {
          rv[t] = rv[t + o]; ri[t] = ri[t + o];
        }
      }
      __syncthreads();
    }
    far = ri[0];
    __syncthreads();
  }
}

// ---------------- 2. kNN (one block per (b,g) center) ----------------
__global__ __launch_bounds__(256) void knn_kernel(const float* __restrict__ xyz,
                                                  const int* __restrict__ cent,
                                                  float* __restrict__ center,
                                                  int* __restrict__ knn) {
  __shared__ float d2s[NPTS];
  __shared__ float rv[256];
  __shared__ int   ri[256];
  const int bg = blockIdx.x, t = threadIdx.x;
  const int b = bg >> 7;
  const float* X = xyz + (size_t)b * NPTS * 3;
  const int ci = cent[bg];
  const float cx = X[ci * 3 + 0], cy = X[ci * 3 + 1], cz = X[ci * 3 + 2];
  if (t == 0) { center[bg * 3 + 0] = cx; center[bg * 3 + 1] = cy; center[bg * 3 + 2] = cz; }
  const float ra = sq3(cx, cy, cz);
  for (int i = t; i < NPTS; i += 256) {
    float x = X[i * 3 + 0], y = X[i * 3 + 1], z = X[i * 3 + 2];
    float rb = sq3(x, y, z);
    float dt = dot3(cx, cy, cz, x, y, z);
    // match reference: max(0, (ra+rb) - 2*dot)
    d2s[i] = fmaxf(__fsub_rn(__fadd_rn(ra, rb), __fmul_rn(2.0f, dt)), 0.0f);
  }
  __syncthreads();
  for (int k = 0; k < NK; ++k) {
    float bv = 3.0e38f; int bi = 0;
    for (int i = t; i < NPTS; i += 256) {
      float v = d2s[i];
      if (v < bv) { bv = v; bi = i; }
    }
    rv[t] = bv; ri[t] = bi;
    __syncthreads();
    for (int o = 128; o > 0; o >>= 1) {
      if (t < o) {
        if (rv[t + o] < rv[t] || (rv[t + o] == rv[t] && ri[t + o] < ri[t])) {
          rv[t] = rv[t + o]; ri[t] = ri[t + o];
        }
      }
      __syncthreads();
    }
    if (t == 0) { knn[(size_t)bg * NK + k] = ri[0]; d2s[ri[0]] = 3.0e38f; }
    __syncthreads();
  }
}

// ---------------- 3. greedy nearest path over centers (one block per batch) ----------------
__global__ __launch_bounds__(128) void order_kernel(const float* __restrict__ center,
                                                    int* __restrict__ order) {
  __shared__ float cx[NG], cy[NG], cz[NG];
  __shared__ int   vis[NG];
  __shared__ float rv[NG];
  __shared__ int   ri[NG];
  const int b = blockIdx.x, t = threadIdx.x;
  cx[t] = center[((size_t)b * NG + t) * 3 + 0];
  cy[t] = center[((size_t)b * NG + t) * 3 + 1];
  cz[t] = center[((size_t)b * NG + t) * 3 + 2];
  vis[t] = (t == 0) ? 1 : 0;
  if (t == 0) order[b * NG] = 0;
  __syncthreads();
  int last = 0;
  for (int s = 1; s < NG; ++s) {
    float d;
    if (vis[t]) {
      d = 3.0e38f;
    } else {
      const float lx = cx[last], ly = cy[last], lz = cz[last];
      float ra = sq3(lx, ly, lz), rb = sq3(cx[t], cy[t], cz[t]);
      float dd = __fsub_rn(__fadd_rn(ra, rb), __fmul_rn(2.0f, dot3(lx, ly, lz, cx[t], cy[t], cz[t])));
      d = fmaxf(dd, 0.0f);
    }
    rv[t] = d; ri[t] = t;
    __syncthreads();
    for (int o = 64; o > 0; o >>= 1) {
      if (t < o) {
        if (rv[t + o] < rv[t] || (rv[t + o] == rv[t] && ri[t + o] < ri[t])) {
          rv[t] = rv[t + o]; ri[t] = ri[t + o];
        }
      }
      __syncthreads();
    }
    last = ri[0];
    if (t == 0) order[b * NG + s] = last;
    if (t == last) vis[t] = 1;
    __syncthreads();
  }
}

// ---------------- 4. gather ordered neighborhoods ----------------
__global__ void gather_neigh(const float* __restrict__ xyz, const int* __restrict__ knn,
                             const int* __restrict__ order, const float* __restrict__ center,
                             float* __restrict__ neigh, float* __restrict__ cord) {
  const int bg = blockIdx.x, t = threadIdx.x;  // 32 threads
  const int b = bg >> 7;
  const int src = order[bg];
  const int sbg = (b << 7) + src;
  const float c0 = center[sbg * 3 + 0], c1 = center[sbg * 3 + 1], c2 = center[sbg * 3 + 2];
  if (t < 3) cord[bg * 3 + t] = center[sbg * 3 + t];
  const int idx = knn[(size_t)sbg * NK + t];
  const float* P = xyz + ((size_t)b * NPTS + idx) * 3;
  float* o = neigh + ((size_t)bg * NK + t) * 3;
  o[0] = __fsub_rn(P[0], c0);
  o[1] = __fsub_rn(P[1], c1);
  o[2] = __fsub_rn(P[2], c2);
}

// ---------------- 5. encoder: BN1 statistics ----------------
__global__ __launch_bounds__(128) void bn1_stats(const float* __restrict__ neigh,
                                                 const float* __restrict__ w,
                                                 const float* __restrict__ bias,
                                                 float* __restrict__ psum,
                                                 float* __restrict__ psq) {
  const int c = threadIdx.x, blk = blockIdx.x;   // 256 blocks x 128 ch
  const float wx = w[c * 3 + 0], wy = w[c * 3 + 1], wz = w[c * 3 + 2], bb = bias[c];
  float s = 0.f, s2 = 0.f;
  const float* nr = neigh + (size_t)blk * 256 * 3;
  for (int r = 0; r < 256; ++r) {
    float y = fmaf(nr[r * 3 + 2], wz, fmaf(nr[r * 3 + 1], wy, fmaf(nr[r * 3 + 0], wx, bb)));
    s += y; s2 = fmaf(y, y, s2);
  }
  psum[c * 256 + blk] = s;
  psq[c * 256 + blk]  = s2;
}

// generic 256-partial BN reduce: A = g*rsqrt(var+eps), B0 = b - mean*A  (M = 65536)
__global__ __launch_bounds__(256) void bn_reduce(const float* __restrict__ psum,
                                                 const float* __restrict__ psq,
                                                 const float* __restrict__ g,
                                                 const float* __restrict__ b,
                                                 float* __restrict__ A, float* __restrict__ B0) {
  __shared__ double rs[256], rq[256];
  const int c = blockIdx.x, t = threadIdx.x;
  rs[t] = (double)psum[c * 256 + t];
  rq[t] = (double)psq[c * 256 + t];
  __syncthreads();
  for (int o = 128; o > 0; o >>= 1) {
    if (t < o) { rs[t] += rs[t + o]; rq[t] += rq[t + o]; }
    __syncthreads();
  }
  if (t == 0) {
    const double M = 65536.0;
    double m = rs[0] / M;
    double v = rq[0] / M - m * m;
    if (v < 0) v = 0;
    float a = g[c] * rsqrtf((float)v + LN_EPS);
    A[c] = a;
    B0[c] = b[c] - (float)m * a;
  }
}

// ---------------- 6. flat encoder stages ----------------
// f1 = relu(bn1(neigh @ ec1w^T)) -> bf16 [65536][128]
__global__ __launch_bounds__(256) void enc_f1(const float* __restrict__ neigh,
                                              const float* __restrict__ ec1w, const float* __restrict__ ec1b,
                                              const float* __restrict__ A1, const float* __restrict__ B01,
                                              unsigned short* __restrict__ f1bf) {
  __shared__ float ns[96];
  const int bg = blockIdx.x, t = threadIdx.x;
  if (t < 96) ns[t] = neigh[(size_t)bg * 96 + t];
  __syncthreads();
  for (int e = t; e < 32 * 128; e += 256) {
    const int r = e >> 7, c = e & 127;
    float y = fmaf(ns[r * 3 + 2], ec1w[c * 3 + 2],
             fmaf(ns[r * 3 + 1], ec1w[c * 3 + 1],
             fmaf(ns[r * 3 + 0], ec1w[c * 3 + 0], ec1b[c])));
    y = fmaxf(fmaf(y, A1[c], B01[c]), 0.f);
    f1bf[(size_t)bg * 4096 + e] = f2bf(y);
  }
}

// per-group column max of f2 [65536][256] -> gmax [2048][256]
__global__ __launch_bounds__(256) void enc_gmax(const unsigned short* __restrict__ f2bf_,
                                                unsigned short* __restrict__ gmaxbf) {
  const int bg = blockIdx.x, t = threadIdx.x;
  const unsigned short* p = f2bf_ + (size_t)bg * 32 * 256 + t;
  float m = bf2f(p[0]);
#pragma unroll 8
  for (int r = 1; r < 32; ++r) m = fmaxf(m, bf2f(p[(size_t)r * 256]));
  gmaxbf[(size_t)bg * 256 + t] = f2bf(m);
}

// per-column sum / sumsq of s3 bf16 [65536][512] -> partials [512][256]
__global__ __launch_bounds__(256) void bn2_stats_flat(const unsigned short* __restrict__ s3,
                                                      float* __restrict__ psum, float* __restrict__ psq) {
  const int blk = blockIdx.x, t = threadIdx.x;  // 256 blocks x 256 rows
  const unsigned short* base = s3 + (size_t)blk * 256 * 512;
#pragma unroll
  for (int cc = 0; cc < 2; ++cc) {
    const int c = t + cc * 256;
    float s = 0.f, q = 0.f;
    for (int r = 0; r < 256; ++r) {
      const float v = bf2f(base[(size_t)r * 512 + c]);
      s += v; q = fmaf(v, v, q);
    }
    psum[(size_t)c * 256 + blk] = s;
    psq[(size_t)c * 256 + blk]  = q;
  }
}

// in-place s3 = bf16(relu(s3*A2+B02))  [65536][512]
__global__ __launch_bounds__(256) void bn2_apply(unsigned short* __restrict__ s3,
                                                 const float* __restrict__ A2,
                                                 const float* __restrict__ B02) {
  const size_t total = (size_t)65536 * 512 / 8;
  for (size_t i = (size_t)blockIdx.x * blockDim.x + threadIdx.x; i < total;
       i += (size_t)gridDim.x * blockDim.x) {
    short8v v = *(short8v*)(s3 + i * 8);
    const int c0 = (int)((i * 8) & 511);
    short8v o;
#pragma unroll
    for (int j = 0; j < 8; ++j) {
      const float x = bf2f((unsigned short)v[j]);
      o[j] = (short)f2bf(fmaxf(fmaf(x, A2[c0 + j], B02[c0 + j]), 0.f));
    }
    *(short8v*)(s3 + i * 8) = o;
  }
}

// per-group row max of t4 bf16 [65536][384] + sc2b -> tokens fp32 [2048][384]
__global__ __launch_bounds__(384) void enc_pool(const unsigned short* __restrict__ t4,
                                                const float* __restrict__ sc2b,
                                                float* __restrict__ tokens) {
  const int bg = blockIdx.x, t = threadIdx.x;  // 384 threads, one col each
  const unsigned short* p = t4 + (size_t)bg * 32 * 384 + t;
  float m = bf2f(p[0]);
#pragma unroll 8
  for (int r = 1; r < 32; ++r) m = fmaxf(m, bf2f(p[(size_t)r * 384]));
  tokens[(size_t)bg * 384 + t] = m + sc2b[t];
}

// ---------------- 8. positional embedding + h init ----------------
__global__ void pos_kernel(const float* __restrict__ cord, float* __restrict__ pos) {
  const int tok = blockIdx.x, t = threadIdx.x;   // 384 threads
  const int c = t >> 7;
  const int rem = t & 127;
  const int i = rem >> 1;
  const int isc = rem & 1;
  const float coord = cord[tok * 3 + c];
  const float ex = 2.0f * (float)i / 128.0f;
  const float inv = 1.0f / powf(10000.0f, ex);
  const float ang = coord * inv;
  pos[(size_t)tok * NC + t] = isc ? cosf(ang) : sinf(ang);
}

__global__ void hinit_kernel(const float* __restrict__ tokens, const float* __restrict__ sos,
                             float* __restrict__ h) {
  const int tok = blockIdx.x, t = threadIdx.x;   // 384 threads
  const int b = tok >> 7, g = tok & 127;
  const float v = (g == 0) ? sos[t] : tokens[((size_t)b * NG + (g - 1)) * NC + t];
  h[(size_t)tok * NC + t] = v;
}

// ---------------- weight fp32 -> bf16 conversion ----------------
__global__ void cvt_bf16(const float* __restrict__ src, unsigned short* __restrict__ dst, int n) {
  for (int i = blockIdx.x * blockDim.x + threadIdx.x; i < n; i += gridDim.x * blockDim.x)
    dst[i] = f2bf(src[i]);
}

// split sc1w [512][512] into gm-half a [512][256] and f2-half b [512][256]
__global__ void cvt_split_sc1w(const float* __restrict__ src,
                               unsigned short* __restrict__ a, unsigned short* __restrict__ b) {
  const int i = blockIdx.x * 256 + threadIdx.x;
  if (i < 512 * 512) {
    const int c = i >> 9, k = i & 511;
    const unsigned short v = f2bf(src[i]);
    if (k < 256) a[c * 256 + k] = v;
    else         b[c * 256 + (k - 256)] = v;
  }
}

// ---------------- 9. layernorm (optionally add first; y fp32 or bf16; optional x copy) ----------------
template <bool BF16OUT>
__global__ __launch_bounds__(128) void ln_kernel(const float* __restrict__ in,
                                                 const float* __restrict__ add,
                                                 const float* __restrict__ g,
                                                 const float* __restrict__ b,
                                                 void* __restrict__ y,
                                                 float* __restrict__ xout) {
  __shared__ float red[128];
  const int row = blockIdx.x, t = threadIdx.x;
  const float* ip = in + (size_t)row * NC;
  float v0 = ip[t], v1 = ip[t + 128], v2 = ip[t + 256];
  if (add) {
    const float* ap = add + (size_t)row * NC;
    v0 += ap[t]; v1 += ap[t + 128]; v2 += ap[t + 256];
  }
  red[t] = v0 + v1 + v2;
  __syncthreads();
  for (int o = 64; o > 0; o >>= 1) { if (t < o) red[t] += red[t + o]; __syncthreads(); }
  const float m = red[0] / (float)NC;
  __syncthreads();
  float d0 = v0 - m, d1 = v1 - m, d2 = v2 - m;
  red[t] = d0 * d0 + d1 * d1 + d2 * d2;
  __syncthreads();
  for (int o = 64; o > 0; o >>= 1) { if (t < o) red[t] += red[t + o]; __syncthreads(); }
  const float rs = rsqrtf(red[0] / (float)NC + LN_EPS);
  const float y0 = d0 * rs * g[t] + b[t];
  const float y1 = d1 * rs * g[t + 128] + b[t + 128];
  const float y2 = d2 * rs * g[t + 256] + b[t + 256];
  if (BF16OUT) {
    unsigned short* yp = (unsigned short*)y + (size_t)row * NC;
    yp[t] = f2bf(y0); yp[t + 128] = f2bf(y1); yp[t + 256] = f2bf(y2);
  } else {
    float* yp = (float*)y + (size_t)row * NC;
    yp[t] = y0; yp[t + 128] = y1; yp[t + 256] = y2;
  }
  if (xout) {
    float* xp = xout + (size_t)row * NC;
    xp[t] = v0; xp[t + 128] = v1; xp[t + 256] = v2;
  }
}

// ---------------- 10. bf16 MFMA GEMM: C = act(A @ W^T + bias) (+res) ----------------
// A: [M][K] bf16 row-major; W: [N][K] bf16 row-major. 64x64 block tile, 4 waves
// at 32x32 (2x2 fragments of 16x16x32). Fragments loaded direct from global
// (operands are L2-resident). acc fp32.
// RESMODE: 0 = none, 1 = += R[m*N+n] (residual), 2 = += R[(m>>5)*N+n] (per-group add)
template <int ACT, int RESMODE, bool OUT_BF>
__global__ __launch_bounds__(256) void gemm_mfma(const unsigned short* __restrict__ A,
                                                 const unsigned short* __restrict__ W,
                                                 const float* __restrict__ bias,
                                                 const float* __restrict__ R,
                                                 void* __restrict__ Cv,
                                                 int N, int K) {
  const int t = threadIdx.x;
  const int lane = t & 63, wid = t >> 6;
  const int wr = wid >> 1, wc = wid & 1;
  const int m0 = blockIdx.y * 64 + wr * 32;
  const int n0 = blockIdx.x * 64 + wc * 32;
  const int lr = lane & 15, kg = lane >> 4;
  const unsigned short* a0p = A + (size_t)(m0 + lr) * K + kg * 8;
  const unsigned short* a1p = a0p + (size_t)16 * K;
  const unsigned short* b0p = W + (size_t)(n0 + lr) * K + kg * 8;
  const unsigned short* b1p = b0p + (size_t)16 * K;
  f32x4 acc00 = {0.f, 0.f, 0.f, 0.f}, acc01 = acc00, acc10 = acc00, acc11 = acc00;
  for (int k0 = 0; k0 < K; k0 += 32) {
    const short8v av0 = *(const short8v*)(a0p + k0);
    const short8v av1 = *(const short8v*)(a1p + k0);
    const short8v bv0 = *(const short8v*)(b0p + k0);
    const short8v bv1 = *(const short8v*)(b1p + k0);
    acc00 = __builtin_amdgcn_mfma_f32_16x16x32_bf16(av0, bv0, acc00, 0, 0, 0);
    acc01 = __builtin_amdgcn_mfma_f32_16x16x32_bf16(av0, bv1, acc01, 0, 0, 0);
    acc10 = __builtin_amdgcn_mfma_f32_16x16x32_bf16(av1, bv0, acc10, 0, 0, 0);
    acc11 = __builtin_amdgcn_mfma_f32_16x16x32_bf16(av1, bv1, acc11, 0, 0, 0);
  }
  // epilogue: D lane map (verified m89): col = lane&15, row = (lane>>4)*4 + reg
#pragma unroll
  for (int i = 0; i < 2; ++i) {
#pragma unroll
    for (int j = 0; j < 2; ++j) {
      const f32x4 a = (i == 0) ? (j == 0 ? acc00 : acc01) : (j == 0 ? acc10 : acc11);
      const int n = n0 + j * 16 + lr;
      const float bn = bias ? bias[n] : 0.f;
#pragma unroll
      for (int r = 0; r < 4; ++r) {
        const int m = m0 + i * 16 + kg * 4 + r;
        float v = a[r] + bn;
        if (ACT == 1) v = 0.5f * v * (1.0f + erff(v * 0.70710678118654752f));
        if (RESMODE == 1) v += R[(size_t)m * N + n];
        if (RESMODE == 2) v += R[(size_t)(m >> 5) * N + n];
        if (OUT_BF) ((unsigned short*)Cv)[(size_t)m * N + n] = f2bf(v);
        else        ((float*)Cv)[(size_t)m * N + n] = v;
      }
    }
  }
}

// ---------------- 11. attention (bf16 qkv, fp32 scores/softmax) ----------------
__global__ __launch_bounds__(256) void attn_scores(const unsigned short* __restrict__ qkv,
                                                   float* __restrict__ sc) {
  __shared__ float qs[32][NDH + 1];
  __shared__ float ks[NG][NDH + 1];
  const int blk = blockIdx.x, t = threadIdx.x;
  const int qt = blk & 3;
  const int h = (blk >> 2) % NH;
  const int b = blk / (4 * NH);
  for (int e = t; e < 32 * NDH; e += 256) {
    const int r = e >> 6, d = e & 63;
    qs[r][d] = bf2f(qkv[((size_t)(b * NG + qt * 32 + r)) * (3 * NC) + h * NDH + d]);
  }
  for (int e = t; e < NG * NDH; e += 256) {
    const int r = e >> 6, d = e & 63;
    ks[r][d] = bf2f(qkv[((size_t)(b * NG + r)) * (3 * NC) + NC + h * NDH + d]);
  }
  __syncthreads();
  for (int e = t; e < 32 * NG; e += 256) {
    const int r = e >> 7, kc = e & 127;
    const int qi = qt * 32 + r;
    float acc = 0.f;
#pragma unroll
    for (int d = 0; d < NDH; ++d) acc = fmaf(qs[r][d], ks[kc][d], acc);
    const float v = (kc <= qi) ? acc * 0.125f : -1e9f;
    sc[(((size_t)(b * NH + h)) * NG + qi) * NG + kc] = v;
  }
}

__global__ __launch_bounds__(128) void softmax_kernel(float* __restrict__ sc) {
  __shared__ float red[128];
  const size_t row = blockIdx.x;
  const int t = threadIdx.x;
  float v = sc[row * NG + t];
  red[t] = v;
  __syncthreads();
  for (int o = 64; o > 0; o >>= 1) { if (t < o) red[t] = fmaxf(red[t], red[t + o]); __syncthreads(); }
  const float m = red[0];
  __syncthreads();
  const float e = expf(v - m);
  red[t] = e;
  __syncthreads();
  for (int o = 64; o > 0; o >>= 1) { if (t < o) red[t] += red[t + o]; __syncthreads(); }
  sc[row * NG + t] = e / red[0];
}

__global__ __launch_bounds__(256) void attn_pv(const unsigned short* __restrict__ qkv,
                                               const float* __restrict__ sc,
                                               unsigned short* __restrict__ obuf) {
  __shared__ float ps[32][NG + 1];
  __shared__ float vs[NG][NDH + 1];
  const int blk = blockIdx.x, t = threadIdx.x;
  const int ot = blk & 3;
  const int h = (blk >> 2) % NH;
  const int b = blk / (4 * NH);
  for (int e = t; e < 32 * NG; e += 256) {
    const int r = e >> 7, kc = e & 127;
    ps[r][kc] = sc[(((size_t)(b * NH + h)) * NG + ot * 32 + r) * NG + kc];
  }
  for (int e = t; e < NG * NDH; e += 256) {
    const int r = e >> 6, d = e & 63;
    vs[r][d] = bf2f(qkv[((size_t)(b * NG + r)) * (3 * NC) + 2 * NC + h * NDH + d]);
  }
  __syncthreads();
  for (int e = t; e < 32 * NDH; e += 256) {
    const int r = e >> 6, d = e & 63;
    float acc = 0.f;
#pragma unroll 8
    for (int k = 0; k < NG; ++k) acc = fmaf(ps[r][k], vs[k][d], acc);
    obuf[((size_t)(b * NG + ot * 32 + r)) * NC + h * NDH + d] = f2bf(acc);
  }
}

// ---------------- launch ----------------
extern "C" void kernel_launch(void* const* d_in, const int* in_sizes, int n_in,
                              void* d_out, int out_size, void* d_ws, size_t ws_size,
                              hipStream_t stream) {
  (void)in_sizes; (void)n_in; (void)out_size; (void)ws_size;
  const float* xyz  = (const float*)d_in[0];
  const float* ec1w = (const float*)d_in[1];
  const float* ec1b = (const float*)d_in[2];
  const float* bn1g = (const float*)d_in[3];
  const float* bn1b = (const float*)d_in[4];
  const float* ec2w = (const float*)d_in[5];
  const float* ec2b = (const float*)d_in[6];
  const float* sc1w = (const float*)d_in[7];
  const float* sc1b = (const float*)d_in[8];
  const float* bn2g = (const float*)d_in[9];
  const float* bn2b = (const float*)d_in[10];
  const float* sc2w = (const float*)d_in[11];
  const float* sc2b = (const float*)d_in[12];
  const float* sos  = (const float*)d_in[13];
  const float* ln1g = (const float*)d_in[14];
  const float* ln1b = (const float*)d_in[15];
  const float* qkvw = (const float*)d_in[16];
  const float* qkvb = (const float*)d_in[17];
  const float* outw = (const float*)d_in[18];
  const float* outb = (const float*)d_in[19];
  const float* ln2g = (const float*)d_in[20];
  const float* ln2b = (const float*)d_in[21];
  const float* m1w  = (const float*)d_in[22];
  const float* m1b  = (const float*)d_in[23];
  const float* m2w  = (const float*)d_in[24];
  const float* m2b  = (const float*)d_in[25];
  const float* lnfg = (const float*)d_in[26];
  const float* lnfb = (const float*)d_in[27];
  float* out = (float*)d_out;

  char* p = (char*)d_ws;
  auto carve = [&](size_t bytes) -> void* {
    void* q = (void*)p;
    p += (bytes + 255) & ~(size_t)255;
    return q;
  };
  int*   cent   = (int*)carve((size_t)NB * NG * 4);
  float* center = (float*)carve((size_t)NB * NG * 3 * 4);
  int*   knn    = (int*)carve((size_t)NB * NG * NK * 4);
  int*   order  = (int*)carve((size_t)NB * NG * 4);
  float* neigh  = (float*)carve((size_t)NB * NG * NK * 3 * 4);
  float* cord   = (float*)carve((size_t)NB * NG * 3 * 4);
  float* psum1  = (float*)carve((size_t)128 * 256 * 4);
  float* psq1   = (float*)carve((size_t)128 * 256 * 4);
  float* A1     = (float*)carve(128 * 4);
  float* B01    = (float*)carve(128 * 4);
  float* psum2  = (float*)carve((size_t)512 * 256 * 4);
  float* psq2   = (float*)carve((size_t)512 * 256 * 4);
  float* A2     = (float*)carve(512 * 4);
  float* B02    = (float*)carve(512 * 4);
  float* tokens = (float*)carve((size_t)NB * NG * NC * 4);
  float* posb   = (float*)carve((size_t)NB * NG * NC * 4);
  float* hbuf   = (float*)carve((size_t)NB * NG * NC * 4);
  float* xbuf   = (float*)carve((size_t)NB * NG * NC * 4);
  float* scbuf  = (float*)carve((size_t)NB * NH * NG * NG * 4);
  unsigned short* ybf    = (unsigned short*)carve((size_t)NB * NG * NC * 2);
  unsigned short* qkv_bf = (unsigned short*)carve((size_t)NB * NG * 3 * NC * 2);
  unsigned short* obf    = (unsigned short*)carve((size_t)NB * NG * NC * 2);
  unsigned short* mh_bf  = (unsigned short*)carve((size_t)NB * NG * NHID * 2);
  unsigned short* wqkv_bf = (unsigned short*)carve((size_t)NL * 3 * NC * NC * 2);
  unsigned short* wout_bf = (unsigned short*)carve((size_t)NL * NC * NC * 2);
  unsigned short* wm1_bf  = (unsigned short*)carve((size_t)NL * NHID * NC * 2);
  unsigned short* wm2_bf  = (unsigned short*)carve((size_t)NL * NC * NHID * 2);
  // encoder bf16 weights
  unsigned short* ec2w_bf = (unsigned short*)carve((size_t)256 * 128 * 2);
  unsigned short* w3a_bf  = (unsigned short*)carve((size_t)512 * 256 * 2);
  unsigned short* w3b_bf  = (unsigned short*)carve((size_t)512 * 256 * 2);
  unsigned short* sc2w_bf = (unsigned short*)carve((size_t)384 * 512 * 2);
  // encoder activations (flat)
  unsigned short* f1bf   = (unsigned short*)carve((size_t)65536 * 128 * 2);  // 16.78 MB
  unsigned short* f2bf_a = (unsigned short*)carve((size_t)65536 * 256 * 2);  // 33.55 MB
  unsigned short* gmaxbf = (unsigned short*)carve((size_t)2048 * 256 * 2);
  float*          sgbuf  = (float*)carve((size_t)2048 * 512 * 4);
  unsigned short* s3bf   = (unsigned short*)carve((size_t)65536 * 512 * 2);  // 67.1 MB
  // t4 (65536*384*2 = 50.33 MB) aliases f1bf+f2bf_a (both dead before g_mm4 writes it)
  unsigned short* t4bf = f1bf;

  const int NTOK = NB * NG;  // 2048

  // weight conversion (deterministic, every call)
  cvt_bf16<<<2048, 256, 0, stream>>>(qkvw, wqkv_bf, NL * 3 * NC * NC);
  cvt_bf16<<<2048, 256, 0, stream>>>(outw, wout_bf, NL * NC * NC);
  cvt_bf16<<<2048, 256, 0, stream>>>(m1w, wm1_bf, NL * NHID * NC);
  cvt_bf16<<<2048, 256, 0, stream>>>(m2w, wm2_bf, NL * NC * NHID);
  cvt_bf16<<<128, 256, 0, stream>>>(ec2w, ec2w_bf, 256 * 128);
  cvt_split_sc1w<<<1024, 256, 0, stream>>>(sc1w, w3a_bf, w3b_bf);
  cvt_bf16<<<768, 256, 0, stream>>>(sc2w, sc2w_bf, 384 * 512);

  fps_kernel<<<NB, 512, 0, stream>>>(xyz, cent);
  knn_kernel<<<NTOK, 256, 0, stream>>>(xyz, cent, center, knn);
  order_kernel<<<NB, 128, 0, stream>>>(center, order);
  gather_neigh<<<NTOK, 32, 0, stream>>>(xyz, knn, order, center, neigh, cord);

  // ---- encoder (flat MFMA pipeline) ----
  bn1_stats<<<256, 128, 0, stream>>>(neigh, ec1w, ec1b, psum1, psq1);
  bn_reduce<<<128, 256, 0, stream>>>(psum1, psq1, bn1g, bn1b, A1, B01);
  enc_f1<<<NTOK, 256, 0, stream>>>(neigh, ec1w, ec1b, A1, B01, f1bf);
  gemm_mfma<0, 0, true><<<dim3(4, 1024), 256, 0, stream>>>(
      f1bf, ec2w_bf, ec2b, nullptr, f2bf_a, 256, 128);
  enc_gmax<<<NTOK, 256, 0, stream>>>(f2bf_a, gmaxbf);
  gemm_mfma<0, 0, false><<<dim3(8, 32), 256, 0, stream>>>(
      gmaxbf, w3a_bf, nullptr, nullptr, sgbuf, 512, 256);
  gemm_mfma<0, 2, true><<<dim3(8, 1024), 256, 0, stream>>>(
      f2bf_a, w3b_bf, sc1b, sgbuf, s3bf, 512, 256);
  bn2_stats_flat<<<256, 256, 0, stream>>>(s3bf, psum2, psq2);
  bn_reduce<<<512, 256, 0, stream>>>(psum2, psq2, bn2g, bn2b, A2, B02);
  bn2_apply<<<4096, 256, 0, stream>>>(s3bf, A2, B02);
  gemm_mfma<0, 0, true><<<dim3(6, 1024), 256, 0, stream>>>(
      s3bf, sc2w_bf, nullptr, nullptr, t4bf, 384, 512);
  enc_pool<<<NTOK, 384, 0, stream>>>(t4bf, sc2b, tokens);

  pos_kernel<<<NTOK, NC, 0, stream>>>(cord, posb);
  hinit_kernel<<<NTOK, NC, 0, stream>>>(tokens, sos, hbuf);

  for (int l = 0; l < NL; ++l) {
    ln_kernel<true><<<NTOK, 128, 0, stream>>>(hbuf, posb, ln1g + l * NC, ln1b + l * NC, ybf, xbuf);
    gemm_mfma<0, 0, true><<<dim3(18, 32), 256, 0, stream>>>(
        ybf, wqkv_bf + (size_t)l * 3 * NC * NC, qkvb + (size_t)l * 3 * NC, nullptr, qkv_bf,
        3 * NC, NC);
    attn_scores<<<NB * NH * 4, 256, 0, stream>>>(qkv_bf, scbuf);
    softmax_kernel<<<NB * NH * NG, 128, 0, stream>>>(scbuf);
    attn_pv<<<NB * NH * 4, 256, 0, stream>>>(qkv_bf, scbuf, obf);
    gemm_mfma<0, 1, false><<<dim3(6, 32), 256, 0, stream>>>(
        obf, wout_bf + (size_t)l * NC * NC, outb + (size_t)l * NC, xbuf, hbuf,
        NC, NC);
    ln_kernel<true><<<NTOK, 128, 0, stream>>>(hbuf, nullptr, ln2g + l * NC, ln2b + l * NC, ybf, nullptr);
    gemm_mfma<1, 0, true><<<dim3(24, 32), 256, 0, stream>>>(
        ybf, wm1_bf + (size_t)l * NHID * NC, m1b + (size_t)l * NHID, nullptr, mh_bf,
        NHID, NC);
    gemm_mfma<0, 1, false><<<dim3(6, 32), 256, 0, stream>>>(
        mh_bf, wm2_bf + (size_t)l * NC * NHID, m2b + (size_t)l * NC, hbuf, hbuf,
        NC, NHID);
  }
  ln_kernel<false><<<NTOK, 128, 0, stream>>>(hbuf, nullptr, lnfg, lnfb, out, nullptr);
}

// Round 9
// 2480.909 us; speedup vs baseline: 3.3760x; 1.1571x over previous
//
#include <hip/hip_runtime.h>
#include <math.h>

#define DEVFN __device__ __forceinline__

constexpr int NB   = 16;     // batch
constexpr int NPTS = 8192;   // N points
constexpr int NG   = 128;    // groups
constexpr int NK   = 32;     // knn
constexpr int NC   = 384;    // model dim
constexpr int NH   = 6;      // heads
constexpr int NL   = 12;     // layers
constexpr int NHID = 1536;   // mlp hidden
constexpr int NDH  = 64;     // head dim
constexpr float LN_EPS = 1e-5f;

typedef __attribute__((ext_vector_type(8))) short short8v;
typedef __attribute__((ext_vector_type(4))) float f32x4;

// fp32 ops without fma contraction, to track numpy's rounding in the
// index-selection stages (FPS / kNN / path ordering).
DEVFN float sq3(float x, float y, float z) {
  return __fadd_rn(__fadd_rn(__fmul_rn(x, x), __fmul_rn(y, y)), __fmul_rn(z, z));
}
DEVFN float dot3(float ax, float ay, float az, float bx, float by, float bz) {
  return __fadd_rn(__fadd_rn(__fmul_rn(ax, bx), __fmul_rn(ay, by)), __fmul_rn(az, bz));
}
DEVFN unsigned short f2bf(float f) {   // RTNE fp32 -> bf16
  unsigned u = __float_as_uint(f);
  return (unsigned short)((u + 0x7fffu + ((u >> 16) & 1u)) >> 16);
}
DEVFN float bf2f(unsigned short u) { return __uint_as_float(((unsigned)u) << 16); }

// ---------------- 1. farthest point sampling (one block per batch) ----------------
// register-resident points + dists; shuffle-butterfly argmax carrying coords.
__global__ __launch_bounds__(512) void fps_kernel(const float* __restrict__ xyz,
                                                  int* __restrict__ cent) {
  __shared__ float swv[8], swx[8], swy[8], swz[8];
  __shared__ int   swi[8];
  const int b = blockIdx.x, t = threadIdx.x;
  const float* X = xyz + (size_t)b * NPTS * 3;
  float px[16], py[16], pz[16], dd[16];
#pragma unroll
  for (int k = 0; k < 16; ++k) {
    const int i = t + k * 512;
    px[k] = X[i * 3 + 0]; py[k] = X[i * 3 + 1]; pz[k] = X[i * 3 + 2];
    dd[k] = 1e10f;
  }
  int far = 0;
  float fx = X[0], fy = X[1], fz = X[2];   // coords of point 0 (broadcast load)
  for (int s = 0; s < NG; ++s) {
    if (t == 0) cent[b * NG + s] = far;
    float bv = -1.0f, bx = 0.f, by = 0.f, bz = 0.f;
    int bi = 0;
#pragma unroll
    for (int k = 0; k < 16; ++k) {
      const float dx = __fsub_rn(px[k], fx);
      const float dy = __fsub_rn(py[k], fy);
      const float dz = __fsub_rn(pz[k], fz);
      const float d  = sq3(dx, dy, dz);
      const float nd = fminf(dd[k], d);
      dd[k] = nd;
      if (nd > bv) { bv = nd; bi = t + k * 512; bx = px[k]; by = py[k]; bz = pz[k]; }
    }
#pragma unroll
    for (int m = 1; m < 64; m <<= 1) {
      const float ov = __shfl_xor(bv, m, 64);
      const int   oi = __shfl_xor(bi, m, 64);
      const float ox = __shfl_xor(bx, m, 64);
      const float oy = __shfl_xor(by, m, 64);
      const float oz = __shfl_xor(bz, m, 64);
      if (ov > bv || (ov == bv && oi < bi)) { bv = ov; bi = oi; bx = ox; by = oy; bz = oz; }
    }
    __syncthreads();   // previous iteration's LDS reads complete
    if ((t & 63) == 0) {
      const int w = t >> 6;
      swv[w] = bv; swi[w] = bi; swx[w] = bx; swy[w] = by; swz[w] = bz;
    }
    __syncthreads();
    float fv = swv[0]; int fi = swi[0];
    fx = swx[0]; fy = swy[0]; fz = swz[0];
#pragma unroll
    for (int w = 1; w < 8; ++w) {
      if (swv[w] > fv || (swv[w] == fv && swi[w] < fi)) {
        fv = swv[w]; fi = swi[w]; fx = swx[w]; fy = swy[w]; fz = swz[w];
      }
    }
    far = fi;
  }
}

// ---------------- 2. kNN (one block per (b,g) center) ----------------
// register-resident d2 + cached local min; per-pass shuffle reduce.
__global__ __launch_bounds__(256) void knn_kernel(const float* __restrict__ xyz,
                                                  const int* __restrict__ cent,
                                                  float* __restrict__ center,
                                                  int* __restrict__ knn) {
  __shared__ float swv[4];
  __shared__ int   swi[4];
  __shared__ float sc[3];
  const int bg = blockIdx.x, t = threadIdx.x;
  const int b = bg >> 7;
  const float* X = xyz + (size_t)b * NPTS * 3;
  if (t == 0) {
    const int ci = cent[bg];
    sc[0] = X[ci * 3 + 0]; sc[1] = X[ci * 3 + 1]; sc[2] = X[ci * 3 + 2];
    center[bg * 3 + 0] = sc[0]; center[bg * 3 + 1] = sc[1]; center[bg * 3 + 2] = sc[2];
  }
  __syncthreads();
  const float cx = sc[0], cy = sc[1], cz = sc[2];
  const float ra = sq3(cx, cy, cz);
  float d[32];
#pragma unroll
  for (int k = 0; k < 32; ++k) {
    const int i = t + k * 256;
    const float x = X[i * 3 + 0], y = X[i * 3 + 1], z = X[i * 3 + 2];
    const float rb = sq3(x, y, z);
    const float dt = dot3(cx, cy, cz, x, y, z);
    d[k] = fmaxf(__fsub_rn(__fadd_rn(ra, rb), __fmul_rn(2.0f, dt)), 0.0f);
  }
  float lv = 3.0e38f; int li = 0;
#pragma unroll
  for (int k = 0; k < 32; ++k) { if (d[k] < lv) { lv = d[k]; li = k; } }
  for (int k = 0; k < NK; ++k) {
    float bv = lv; int bi = t + li * 256;
#pragma unroll
    for (int m = 1; m < 64; m <<= 1) {
      const float ov = __shfl_xor(bv, m, 64);
      const int   oi = __shfl_xor(bi, m, 64);
      if (ov < bv || (ov == bv && oi < bi)) { bv = ov; bi = oi; }
    }
    __syncthreads();
    if ((t & 63) == 0) { swv[t >> 6] = bv; swi[t >> 6] = bi; }
    __syncthreads();
    float fv = swv[0]; int fi = swi[0];
#pragma unroll
    for (int w = 1; w < 4; ++w) {
      if (swv[w] < fv || (swv[w] == fv && swi[w] < fi)) { fv = swv[w]; fi = swi[w]; }
    }
    if (t == 0) knn[(size_t)bg * NK + k] = fi;
    if ((fi & 255) == t) {
      const int kk = fi >> 8;
#pragma unroll
      for (int j = 0; j < 32; ++j) if (j == kk) d[j] = 3.0e38f;   // compile-time indices
      lv = 3.0e38f; li = 0;
#pragma unroll
      for (int j = 0; j < 32; ++j) { if (d[j] < lv) { lv = d[j]; li = j; } }
    }
  }
}

// ---------------- 3. greedy nearest path over centers (one block per batch) ----------------
__global__ __launch_bounds__(128) void order_kernel(const float* __restrict__ center,
                                                    int* __restrict__ order) {
  __shared__ float cx[NG], cy[NG], cz[NG];
  __shared__ int   vis[NG];
  __shared__ float rv[NG];
  __shared__ int   ri[NG];
  const int b = blockIdx.x, t = threadIdx.x;
  cx[t] = center[((size_t)b * NG + t) * 3 + 0];
  cy[t] = center[((size_t)b * NG + t) * 3 + 1];
  cz[t] = center[((size_t)b * NG + t) * 3 + 2];
  vis[t] = (t == 0) ? 1 : 0;
  if (t == 0) order[b * NG] = 0;
  __syncthreads();
  int last = 0;
  for (int s = 1; s < NG; ++s) {
    float d;
    if (vis[t]) {
      d = 3.0e38f;
    } else {
      const float lx = cx[last], ly = cy[last], lz = cz[last];
      float ra = sq3(lx, ly, lz), rb = sq3(cx[t], cy[t], cz[t]);
      float dd = __fsub_rn(__fadd_rn(ra, rb), __fmul_rn(2.0f, dot3(lx, ly, lz, cx[t], cy[t], cz[t])));
      d = fmaxf(dd, 0.0f);
    }
    rv[t] = d; ri[t] = t;
    __syncthreads();
    for (int o = 64; o > 0; o >>= 1) {
      if (t < o) {
        if (rv[t + o] < rv[t] || (rv[t + o] == rv[t] && ri[t + o] < ri[t])) {
          rv[t] = rv[t + o]; ri[t] = ri[t + o];
        }
      }
      __syncthreads();
    }
    last = ri[0];
    if (t == 0) order[b * NG + s] = last;
    if (t == last) vis[t] = 1;
    __syncthreads();
  }
}

// ---------------- 4. gather ordered neighborhoods ----------------
__global__ void gather_neigh(const float* __restrict__ xyz, const int* __restrict__ knn,
                             const int* __restrict__ order, const float* __restrict__ center,
                             float* __restrict__ neigh, float* __restrict__ cord) {
  const int bg = blockIdx.x, t = threadIdx.x;  // 32 threads
  const int b = bg >> 7;
  const int src = order[bg];
  const int sbg = (b << 7) + src;
  const float c0 = center[sbg * 3 + 0], c1 = center[sbg * 3 + 1], c2 = center[sbg * 3 + 2];
  if (t < 3) cord[bg * 3 + t] = center[sbg * 3 + t];
  const int idx = knn[(size_t)sbg * NK + t];
  const float* P = xyz + ((size_t)b * NPTS + idx) * 3;
  float* o = neigh + ((size_t)bg * NK + t) * 3;
  o[0] = __fsub_rn(P[0], c0);
  o[1] = __fsub_rn(P[1], c1);
  o[2] = __fsub_rn(P[2], c2);
}

// ---------------- 5. encoder: BN1 statistics ----------------
__global__ __launch_bounds__(128) void bn1_stats(const float* __restrict__ neigh,
                                                 const float* __restrict__ w,
                                                 const float* __restrict__ bias,
                                                 float* __restrict__ psum,
                                                 float* __restrict__ psq) {
  const int c = threadIdx.x, blk = blockIdx.x;   // 256 blocks x 128 ch
  const float wx = w[c * 3 + 0], wy = w[c * 3 + 1], wz = w[c * 3 + 2], bb = bias[c];
  float s = 0.f, s2 = 0.f;
  const float* nr = neigh + (size_t)blk * 256 * 3;
  for (int r = 0; r < 256; ++r) {
    float y = fmaf(nr[r * 3 + 2], wz, fmaf(nr[r * 3 + 1], wy, fmaf(nr[r * 3 + 0], wx, bb)));
    s += y; s2 = fmaf(y, y, s2);
  }
  psum[c * 256 + blk] = s;
  psq[c * 256 + blk]  = s2;
}

// generic 256-partial BN reduce: A = g*rsqrt(var+eps), B0 = b - mean*A  (M = 65536)
__global__ __launch_bounds__(256) void bn_reduce(const float* __restrict__ psum,
                                                 const float* __restrict__ psq,
                                                 const float* __restrict__ g,
                                                 const float* __restrict__ b,
                                                 float* __restrict__ A, float* __restrict__ B0) {
  __shared__ double rs[256], rq[256];
  const int c = blockIdx.x, t = threadIdx.x;
  rs[t] = (double)psum[c * 256 + t];
  rq[t] = (double)psq[c * 256 + t];
  __syncthreads();
  for (int o = 128; o > 0; o >>= 1) {
    if (t < o) { rs[t] += rs[t + o]; rq[t] += rq[t + o]; }
    __syncthreads();
  }
  if (t == 0) {
    const double M = 65536.0;
    double m = rs[0] / M;
    double v = rq[0] / M - m * m;
    if (v < 0) v = 0;
    float a = g[c] * rsqrtf((float)v + LN_EPS);
    A[c] = a;
    B0[c] = b[c] - (float)m * a;
  }
}

// ---------------- 6. flat encoder stages ----------------
// f1 = relu(bn1(neigh @ ec1w^T)) -> bf16 [65536][128]
__global__ __launch_bounds__(256) void enc_f1(const float* __restrict__ neigh,
                                              const float* __restrict__ ec1w, const float* __restrict__ ec1b,
                                              const float* __restrict__ A1, const float* __restrict__ B01,
                                              unsigned short* __restrict__ f1bf) {
  __shared__ float ns[96];
  const int bg = blockIdx.x, t = threadIdx.x;
  if (t < 96) ns[t] = neigh[(size_t)bg * 96 + t];
  __syncthreads();
  for (int e = t; e < 32 * 128; e += 256) {
    const int r = e >> 7, c = e & 127;
    float y = fmaf(ns[r * 3 + 2], ec1w[c * 3 + 2],
             fmaf(ns[r * 3 + 1], ec1w[c * 3 + 1],
             fmaf(ns[r * 3 + 0], ec1w[c * 3 + 0], ec1b[c])));
    y = fmaxf(fmaf(y, A1[c], B01[c]), 0.f);
    f1bf[(size_t)bg * 4096 + e] = f2bf(y);
  }
}

// per-group column max of f2 [65536][256] -> gmax [2048][256]
__global__ __launch_bounds__(256) void enc_gmax(const unsigned short* __restrict__ f2bf_,
                                                unsigned short* __restrict__ gmaxbf) {
  const int bg = blockIdx.x, t = threadIdx.x;
  const unsigned short* p = f2bf_ + (size_t)bg * 32 * 256 + t;
  float m = bf2f(p[0]);
#pragma unroll 8
  for (int r = 1; r < 32; ++r) m = fmaxf(m, bf2f(p[(size_t)r * 256]));
  gmaxbf[(size_t)bg * 256 + t] = f2bf(m);
}

// per-column sum / sumsq of s3 bf16 [65536][512] -> partials [512][256]
__global__ __launch_bounds__(256) void bn2_stats_flat(const unsigned short* __restrict__ s3,
                                                      float* __restrict__ psum, float* __restrict__ psq) {
  const int blk = blockIdx.x, t = threadIdx.x;  // 256 blocks x 256 rows
  const unsigned short* base = s3 + (size_t)blk * 256 * 512;
#pragma unroll
  for (int cc = 0; cc < 2; ++cc) {
    const int c = t + cc * 256;
    float s = 0.f, q = 0.f;
    for (int r = 0; r < 256; ++r) {
      const float v = bf2f(base[(size_t)r * 512 + c]);
      s += v; q = fmaf(v, v, q);
    }
    psum[(size_t)c * 256 + blk] = s;
    psq[(size_t)c * 256 + blk]  = q;
  }
}

// in-place s3 = bf16(relu(s3*A2+B02))  [65536][512]
__global__ __launch_bounds__(256) void bn2_apply(unsigned short* __restrict__ s3,
                                                 const float* __restrict__ A2,
                                                 const float* __restrict__ B02) {
  const size_t total = (size_t)65536 * 512 / 8;
  for (size_t i = (size_t)blockIdx.x * blockDim.x + threadIdx.x; i < total;
       i += (size_t)gridDim.x * blockDim.x) {
    short8v v = *(short8v*)(s3 + i * 8);
    const int c0 = (int)((i * 8) & 511);
    short8v o;
#pragma unroll
    for (int j = 0; j < 8; ++j) {
      const float x = bf2f((unsigned short)v[j]);
      o[j] = (short)f2bf(fmaxf(fmaf(x, A2[c0 + j], B02[c0 + j]), 0.f));
    }
    *(short8v*)(s3 + i * 8) = o;
  }
}

// per-group row max of t4 bf16 [65536][384] + sc2b -> tokens fp32 [2048][384]
__global__ __launch_bounds__(384) void enc_pool(const unsigned short* __restrict__ t4,
                                                const float* __restrict__ sc2b,
                                                float* __restrict__ tokens) {
  const int bg = blockIdx.x, t = threadIdx.x;  // 384 threads, one col each
  const unsigned short* p = t4 + (size_t)bg * 32 * 384 + t;
  float m = bf2f(p[0]);
#pragma unroll 8
  for (int r = 1; r < 32; ++r) m = fmaxf(m, bf2f(p[(size_t)r * 384]));
  tokens[(size_t)bg * 384 + t] = m + sc2b[t];
}

// ---------------- 8. positional embedding + h init ----------------
__global__ void pos_kernel(const float* __restrict__ cord, float* __restrict__ pos) {
  const int tok = blockIdx.x, t = threadIdx.x;   // 384 threads
  const int c = t >> 7;
  const int rem = t & 127;
  const int i = rem >> 1;
  const int isc = rem & 1;
  const float coord = cord[tok * 3 + c];
  const float ex = 2.0f * (float)i / 128.0f;
  const float inv = 1.0f / powf(10000.0f, ex);
  const float ang = coord * inv;
  pos[(size_t)tok * NC + t] = isc ? cosf(ang) : sinf(ang);
}

__global__ void hinit_kernel(const float* __restrict__ tokens, const float* __restrict__ sos,
                             float* __restrict__ h) {
  const int tok = blockIdx.x, t = threadIdx.x;   // 384 threads
  const int b = tok >> 7, g = tok & 127;
  const float v = (g == 0) ? sos[t] : tokens[((size_t)b * NG + (g - 1)) * NC + t];
  h[(size_t)tok * NC + t] = v;
}

// ---------------- weight fp32 -> bf16 conversion ----------------
__global__ void cvt_bf16(const float* __restrict__ src, unsigned short* __restrict__ dst, int n) {
  for (int i = blockIdx.x * blockDim.x + threadIdx.x; i < n; i += gridDim.x * blockDim.x)
    dst[i] = f2bf(src[i]);
}

// split sc1w [512][512] into gm-half a [512][256] and f2-half b [512][256]
__global__ void cvt_split_sc1w(const float* __restrict__ src,
                               unsigned short* __restrict__ a, unsigned short* __restrict__ b) {
  const int i = blockIdx.x * 256 + threadIdx.x;
  if (i < 512 * 512) {
    const int c = i >> 9, k = i & 511;
    const unsigned short v = f2bf(src[i]);
    if (k < 256) a[c * 256 + k] = v;
    else         b[c * 256 + (k - 256)] = v;
  }
}

// ---------------- 9. layernorm (optionally add first; y fp32 or bf16; optional x copy) ----------------
template <bool BF16OUT>
__global__ __launch_bounds__(128) void ln_kernel(const float* __restrict__ in,
                                                 const float* __restrict__ add,
                                                 const float* __restrict__ g,
                                                 const float* __restrict__ b,
                                                 void* __restrict__ y,
                                                 float* __restrict__ xout) {
  __shared__ float red[128];
  const int row = blockIdx.x, t = threadIdx.x;
  const float* ip = in + (size_t)row * NC;
  float v0 = ip[t], v1 = ip[t + 128], v2 = ip[t + 256];
  if (add) {
    const float* ap = add + (size_t)row * NC;
    v0 += ap[t]; v1 += ap[t + 128]; v2 += ap[t + 256];
  }
  red[t] = v0 + v1 + v2;
  __syncthreads();
  for (int o = 64; o > 0; o >>= 1) { if (t < o) red[t] += red[t + o]; __syncthreads(); }
  const float m = red[0] / (float)NC;
  __syncthreads();
  float d0 = v0 - m, d1 = v1 - m, d2 = v2 - m;
  red[t] = d0 * d0 + d1 * d1 + d2 * d2;
  __syncthreads();
  for (int o = 64; o > 0; o >>= 1) { if (t < o) red[t] += red[t + o]; __syncthreads(); }
  const float rs = rsqrtf(red[0] / (float)NC + LN_EPS);
  const float y0 = d0 * rs * g[t] + b[t];
  const float y1 = d1 * rs * g[t + 128] + b[t + 128];
  const float y2 = d2 * rs * g[t + 256] + b[t + 256];
  if (BF16OUT) {
    unsigned short* yp = (unsigned short*)y + (size_t)row * NC;
    yp[t] = f2bf(y0); yp[t + 128] = f2bf(y1); yp[t + 256] = f2bf(y2);
  } else {
    float* yp = (float*)y + (size_t)row * NC;
    yp[t] = y0; yp[t + 128] = y1; yp[t + 256] = y2;
  }
  if (xout) {
    float* xp = xout + (size_t)row * NC;
    xp[t] = v0; xp[t + 128] = v1; xp[t + 256] = v2;
  }
}

// ---------------- 10. bf16 MFMA GEMM: C = act(A @ W^T + bias) (+res) ----------------
// A: [M][K] bf16 row-major; W: [N][K] bf16 row-major. 64x64 block tile, 4 waves
// at 32x32 (2x2 fragments of 16x16x32). Fragments loaded direct from global
// (operands are L2-resident). acc fp32. K compile-time for load pipelining.
// RESMODE: 0 = none, 1 = += R[m*N+n] (residual), 2 = += R[(m>>5)*N+n] (per-group add)
template <int ACT, int RESMODE, bool OUT_BF, int K>
__global__ __launch_bounds__(256) void gemm_mfma(const unsigned short* __restrict__ A,
                                                 const unsigned short* __restrict__ W,
                                                 const float* __restrict__ bias,
                                                 const float* __restrict__ R,
                                                 void* __restrict__ Cv,
                                                 int N) {
  const int t = threadIdx.x;
  const int lane = t & 63, wid = t >> 6;
  const int wr = wid >> 1, wc = wid & 1;
  const int m0 = blockIdx.y * 64 + wr * 32;
  const int n0 = blockIdx.x * 64 + wc * 32;
  const int lr = lane & 15, kg = lane >> 4;
  const unsigned short* a0p = A + (size_t)(m0 + lr) * K + kg * 8;
  const unsigned short* a1p = a0p + (size_t)16 * K;
  const unsigned short* b0p = W + (size_t)(n0 + lr) * K + kg * 8;
  const unsigned short* b1p = b0p + (size_t)16 * K;
  f32x4 acc00 = {0.f, 0.f, 0.f, 0.f}, acc01 = acc00, acc10 = acc00, acc11 = acc00;
#pragma unroll 2
  for (int k0 = 0; k0 < K; k0 += 32) {
    const short8v av0 = *(const short8v*)(a0p + k0);
    const short8v av1 = *(const short8v*)(a1p + k0);
    const short8v bv0 = *(const short8v*)(b0p + k0);
    const short8v bv1 = *(const short8v*)(b1p + k0);
    acc00 = __builtin_amdgcn_mfma_f32_16x16x32_bf16(av0, bv0, acc00, 0, 0, 0);
    acc01 = __builtin_amdgcn_mfma_f32_16x16x32_bf16(av0, bv1, acc01, 0, 0, 0);
    acc10 = __builtin_amdgcn_mfma_f32_16x16x32_bf16(av1, bv0, acc10, 0, 0, 0);
    acc11 = __builtin_amdgcn_mfma_f32_16x16x32_bf16(av1, bv1, acc11, 0, 0, 0);
  }
  // epilogue: D lane map (verified m89): col = lane&15, row = (lane>>4)*4 + reg
#pragma unroll
  for (int i = 0; i < 2; ++i) {
#pragma unroll
    for (int j = 0; j < 2; ++j) {
      const f32x4 a = (i == 0) ? (j == 0 ? acc00 : acc01) : (j == 0 ? acc10 : acc11);
      const int n = n0 + j * 16 + lr;
      const float bn = bias ? bias[n] : 0.f;
#pragma unroll
      for (int r = 0; r < 4; ++r) {
        const int m = m0 + i * 16 + kg * 4 + r;
        float v = a[r] + bn;
        if (ACT == 1) v = 0.5f * v * (1.0f + erff(v * 0.70710678118654752f));
        if (RESMODE == 1) v += R[(size_t)m * N + n];
        if (RESMODE == 2) v += R[(size_t)(m >> 5) * N + n];
        if (OUT_BF) ((unsigned short*)Cv)[(size_t)m * N + n] = f2bf(v);
        else        ((float*)Cv)[(size_t)m * N + n] = v;
      }
    }
  }
}

// ---------------- 11. fused attention: scores + softmax + PV (one block per (b,h,qt)) ----------------
__global__ __launch_bounds__(256) void attn_fused(const unsigned short* __restrict__ qkv,
                                                  unsigned short* __restrict__ obuf) {
  __shared__ float qs[32][NDH + 1];
  __shared__ float kv[NG][NDH + 1];   // K first, then overwritten with V
  __shared__ float ps[32][NG + 2];
  const int blk = blockIdx.x, t = threadIdx.x;
  const int qt = blk & 3;
  const int h = (blk >> 2) % NH;
  const int b = blk / (4 * NH);
  for (int e = t; e < 32 * NDH; e += 256) {
    const int r = e >> 6, dc = e & 63;
    qs[r][dc] = bf2f(qkv[((size_t)(b * NG + qt * 32 + r)) * (3 * NC) + h * NDH + dc]);
  }
  for (int e = t; e < NG * NDH; e += 256) {
    const int r = e >> 6, dc = e & 63;
    kv[r][dc] = bf2f(qkv[((size_t)(b * NG + r)) * (3 * NC) + NC + h * NDH + dc]);
  }
  __syncthreads();
  for (int e = t; e < 32 * NG; e += 256) {
    const int r = e >> 7, kc = e & 127;
    const int qi = qt * 32 + r;
    float acc = 0.f;
#pragma unroll
    for (int dd = 0; dd < NDH; ++dd) acc = fmaf(qs[r][dd], kv[kc][dd], acc);
    ps[r][kc] = (kc <= qi) ? acc * 0.125f : -1e9f;
  }
  __syncthreads();
  {
    // softmax: 8 lanes per row (rows of 8 consecutive lanes stay in one wave)
    const int r = t >> 3, ls = t & 7;
    float mx = -3.0e38f;
#pragma unroll
    for (int j = 0; j < 16; ++j) mx = fmaxf(mx, ps[r][ls * 16 + j]);
#pragma unroll
    for (int m = 1; m < 8; m <<= 1) mx = fmaxf(mx, __shfl_xor(mx, m, 64));
    float ev[16], sum = 0.f;
#pragma unroll
    for (int j = 0; j < 16; ++j) { ev[j] = expf(ps[r][ls * 16 + j] - mx); sum += ev[j]; }
#pragma unroll
    for (int m = 1; m < 8; m <<= 1) sum += __shfl_xor(sum, m, 64);
#pragma unroll
    for (int j = 0; j < 16; ++j) ps[r][ls * 16 + j] = ev[j] / sum;
  }
  __syncthreads();
  for (int e = t; e < NG * NDH; e += 256) {   // stage V over K
    const int r = e >> 6, dc = e & 63;
    kv[r][dc] = bf2f(qkv[((size_t)(b * NG + r)) * (3 * NC) + 2 * NC + h * NDH + dc]);
  }
  __syncthreads();
  for (int e = t; e < 32 * NDH; e += 256) {
    const int r = e >> 6, dc = e & 63;
    float acc = 0.f;
#pragma unroll 8
    for (int k = 0; k < NG; ++k) acc = fmaf(ps[r][k], kv[k][dc], acc);
    obuf[((size_t)(b * NG + qt * 32 + r)) * NC + h * NDH + dc] = f2bf(acc);
  }
}

// ---------------- launch ----------------
extern "C" void kernel_launch(void* const* d_in, const int* in_sizes, int n_in,
                              void* d_out, int out_size, void* d_ws, size_t ws_size,
                              hipStream_t stream) {
  (void)in_sizes; (void)n_in; (void)out_size; (void)ws_size;
  const float* xyz  = (const float*)d_in[0];
  const float* ec1w = (const float*)d_in[1];
  const float* ec1b = (const float*)d_in[2];
  const float* bn1g = (const float*)d_in[3];
  const float* bn1b = (const float*)d_in[4];
  const float* ec2w = (const float*)d_in[5];
  const float* ec2b = (const float*)d_in[6];
  const float* sc1w = (const float*)d_in[7];
  const float* sc1b = (const float*)d_in[8];
  const float* bn2g = (const float*)d_in[9];
  const float* bn2b = (const float*)d_in[10];
  const float* sc2w = (const float*)d_in[11];
  const float* sc2b = (const float*)d_in[12];
  const float* sos  = (const float*)d_in[13];
  const float* ln1g = (const float*)d_in[14];
  const float* ln1b = (const float*)d_in[15];
  const float* qkvw = (const float*)d_in[16];
  const float* qkvb = (const float*)d_in[17];
  const float* outw = (const float*)d_in[18];
  const float* outb = (const float*)d_in[19];
  const float* ln2g = (const float*)d_in[20];
  const float* ln2b = (const float*)d_in[21];
  const float* m1w  = (const float*)d_in[22];
  const float* m1b  = (const float*)d_in[23];
  const float* m2w  = (const float*)d_in[24];
  const float* m2b  = (const float*)d_in[25];
  const float* lnfg = (const float*)d_in[26];
  const float* lnfb = (const float*)d_in[27];
  float* out = (float*)d_out;

  char* p = (char*)d_ws;
  auto carve = [&](size_t bytes) -> void* {
    void* q = (void*)p;
    p += (bytes + 255) & ~(size_t)255;
    return q;
  };
  int*   cent   = (int*)carve((size_t)NB * NG * 4);
  float* center = (float*)carve((size_t)NB * NG * 3 * 4);
  int*   knn    = (int*)carve((size_t)NB * NG * NK * 4);
  int*   order  = (int*)carve((size_t)NB * NG * 4);
  float* neigh  = (float*)carve((size_t)NB * NG * NK * 3 * 4);
  float* cord   = (float*)carve((size_t)NB * NG * 3 * 4);
  float* psum1  = (float*)carve((size_t)128 * 256 * 4);
  float* psq1   = (float*)carve((size_t)128 * 256 * 4);
  float* A1     = (float*)carve(128 * 4);
  float* B01    = (float*)carve(128 * 4);
  float* psum2  = (float*)carve((size_t)512 * 256 * 4);
  float* psq2   = (float*)carve((size_t)512 * 256 * 4);
  float* A2     = (float*)carve(512 * 4);
  float* B02    = (float*)carve(512 * 4);
  float* tokens = (float*)carve((size_t)NB * NG * NC * 4);
  float* posb   = (float*)carve((size_t)NB * NG * NC * 4);
  float* hbuf   = (float*)carve((size_t)NB * NG * NC * 4);
  float* xbuf   = (float*)carve((size_t)NB * NG * NC * 4);
  unsigned short* ybf    = (unsigned short*)carve((size_t)NB * NG * NC * 2);
  unsigned short* qkv_bf = (unsigned short*)carve((size_t)NB * NG * 3 * NC * 2);
  unsigned short* obf    = (unsigned short*)carve((size_t)NB * NG * NC * 2);
  unsigned short* mh_bf  = (unsigned short*)carve((size_t)NB * NG * NHID * 2);
  unsigned short* wqkv_bf = (unsigned short*)carve((size_t)NL * 3 * NC * NC * 2);
  unsigned short* wout_bf = (unsigned short*)carve((size_t)NL * NC * NC * 2);
  unsigned short* wm1_bf  = (unsigned short*)carve((size_t)NL * NHID * NC * 2);
  unsigned short* wm2_bf  = (unsigned short*)carve((size_t)NL * NC * NHID * 2);
  // encoder bf16 weights
  unsigned short* ec2w_bf = (unsigned short*)carve((size_t)256 * 128 * 2);
  unsigned short* w3a_bf  = (unsigned short*)carve((size_t)512 * 256 * 2);
  unsigned short* w3b_bf  = (unsigned short*)carve((size_t)512 * 256 * 2);
  unsigned short* sc2w_bf = (unsigned short*)carve((size_t)384 * 512 * 2);
  // encoder activations (flat)
  unsigned short* f1bf   = (unsigned short*)carve((size_t)65536 * 128 * 2);  // 16.78 MB
  unsigned short* f2bf_a = (unsigned short*)carve((size_t)65536 * 256 * 2);  // 33.55 MB
  unsigned short* gmaxbf = (unsigned short*)carve((size_t)2048 * 256 * 2);
  float*          sgbuf  = (float*)carve((size_t)2048 * 512 * 4);
  unsigned short* s3bf   = (unsigned short*)carve((size_t)65536 * 512 * 2);  // 67.1 MB
  // t4 (65536*384*2 = 50.33 MB) aliases f1bf+f2bf_a (both dead before g_mm4 writes it)
  unsigned short* t4bf = f1bf;

  const int NTOK = NB * NG;  // 2048

  // weight conversion (deterministic, every call)
  cvt_bf16<<<2048, 256, 0, stream>>>(qkvw, wqkv_bf, NL * 3 * NC * NC);
  cvt_bf16<<<2048, 256, 0, stream>>>(outw, wout_bf, NL * NC * NC);
  cvt_bf16<<<2048, 256, 0, stream>>>(m1w, wm1_bf, NL * NHID * NC);
  cvt_bf16<<<2048, 256, 0, stream>>>(m2w, wm2_bf, NL * NC * NHID);
  cvt_bf16<<<128, 256, 0, stream>>>(ec2w, ec2w_bf, 256 * 128);
  cvt_split_sc1w<<<1024, 256, 0, stream>>>(sc1w, w3a_bf, w3b_bf);
  cvt_bf16<<<768, 256, 0, stream>>>(sc2w, sc2w_bf, 384 * 512);

  fps_kernel<<<NB, 512, 0, stream>>>(xyz, cent);
  knn_kernel<<<NTOK, 256, 0, stream>>>(xyz, cent, center, knn);
  order_kernel<<<NB, 128, 0, stream>>>(center, order);
  gather_neigh<<<NTOK, 32, 0, stream>>>(xyz, knn, order, center, neigh, cord);

  // ---- encoder (flat MFMA pipeline) ----
  bn1_stats<<<256, 128, 0, stream>>>(neigh, ec1w, ec1b, psum1, psq1);
  bn_reduce<<<128, 256, 0, stream>>>(psum1, psq1, bn1g, bn1b, A1, B01);
  enc_f1<<<NTOK, 256, 0, stream>>>(neigh, ec1w, ec1b, A1, B01, f1bf);
  gemm_mfma<0, 0, true, 128><<<dim3(4, 1024), 256, 0, stream>>>(
      f1bf, ec2w_bf, ec2b, nullptr, f2bf_a, 256);
  enc_gmax<<<NTOK, 256, 0, stream>>>(f2bf_a, gmaxbf);
  gemm_mfma<0, 0, false, 256><<<dim3(8, 32), 256, 0, stream>>>(
      gmaxbf, w3a_bf, nullptr, nullptr, sgbuf, 512);
  gemm_mfma<0, 2, true, 256><<<dim3(8, 1024), 256, 0, stream>>>(
      f2bf_a, w3b_bf, sc1b, sgbuf, s3bf, 512);
  bn2_stats_flat<<<256, 256, 0, stream>>>(s3bf, psum2, psq2);
  bn_reduce<<<512, 256, 0, stream>>>(psum2, psq2, bn2g, bn2b, A2, B02);
  bn2_apply<<<4096, 256, 0, stream>>>(s3bf, A2, B02);
  gemm_mfma<0, 0, true, 512><<<dim3(6, 1024), 256, 0, stream>>>(
      s3bf, sc2w_bf, nullptr, nullptr, t4bf, 384);
  enc_pool<<<NTOK, 384, 0, stream>>>(t4bf, sc2b, tokens);

  pos_kernel<<<NTOK, NC, 0, stream>>>(cord, posb);
  hinit_kernel<<<NTOK, NC, 0, stream>>>(tokens, sos, hbuf);

  for (int l = 0; l < NL; ++l) {
    ln_kernel<true><<<NTOK, 128, 0, stream>>>(hbuf, posb, ln1g + l * NC, ln1b + l * NC, ybf, xbuf);
    gemm_mfma<0, 0, true, 384><<<dim3(18, 32), 256, 0, stream>>>(
        ybf, wqkv_bf + (size_t)l * 3 * NC * NC, qkvb + (size_t)l * 3 * NC, nullptr, qkv_bf,
        3 * NC);
    attn_fused<<<NB * NH * 4, 256, 0, stream>>>(qkv_bf, obf);
    gemm_mfma<0, 1, false, 384><<<dim3(6, 32), 256, 0, stream>>>(
        obf, wout_bf + (size_t)l * NC * NC, outb + (size_t)l * NC, xbuf, hbuf,
        NC);
    ln_kernel<true><<<NTOK, 128, 0, stream>>>(hbuf, nullptr, ln2g + l * NC, ln2b + l * NC, ybf, nullptr);
    gemm_mfma<1, 0, true, 384><<<dim3(24, 32), 256, 0, stream>>>(
        ybf, wm1_bf + (size_t)l * NHID * NC, m1b + (size_t)l * NHID, nullptr, mh_bf,
        NHID);
    gemm_mfma<0, 1, false, 1536><<<dim3(6, 32), 256, 0, stream>>>(
        mh_bf, wm2_bf + (size_t)l * NC * NHID, m2b + (size_t)l * NC, hbuf, hbuf,
        NC);
  }
  ln_kernel<false><<<NTOK, 128, 0, stream>>>(hbuf, nullptr, lnfg, lnfb, out, nullptr);
}